// Round 1
// baseline (2460.192 us; speedup 1.0000x reference)
//
#include <hip/hip_runtime.h>
#include <math.h>

// ---------------------------------------------------------------------------
// MonLipLayer forward on MI355X.
// Pipeline: norms -> scaled W -> A = U-U^T+V^T V -> M=I+A inverted by
// Newton-Schulz (bf16 phase + 2 split-precision iters) -> Cayley Q/R mats
// (bf16) -> main bf16 MFMA chain (x@Q^T, 8 layers, yh@Q) with fused epilogues.
// All GEMMs: C = alpha * A(MxK,row) * Bt(NxK,row)^T + beta * D.
// ---------------------------------------------------------------------------

using s8v  = __attribute__((ext_vector_type(8))) short;   // 8 x bf16
using f4v  = __attribute__((ext_vector_type(4))) float;

#define DEV __device__ __forceinline__

DEV float b2f(unsigned short u){ union{unsigned int i; float f;} v; v.i = ((unsigned int)u)<<16; return v.f; }
DEV unsigned short f2b(float f){
  union{float f; unsigned int i;} v; v.f = f;
  unsigned int u = v.i;
  return (unsigned short)((u + 0x7fffu + ((u>>16)&1u)) >> 16);
}

struct GA {
  const unsigned short* A0h; const unsigned short* A0l; long lda0;
  const unsigned short* A1h; const unsigned short* A1l; long lda1; int ksplit;
  const unsigned short* Bh;  const unsigned short* Bl;  long ldb;
  int K;
  float alpha, beta;
  long sA, sB, sO, sD;
  void* o0; void* o1; void* o2; void* o3; void* o4;
  const void* e0; const void* e1;
  long ldo0, ldo1, ldE;
};

enum { E_F32=0, E_BF16=1, E_BF16T2=2, E_SPLIT=3, E_QW=4, E_PRE=5, E_GH=6, E_OUT=7 };

template<int BM, int BN, int EPI, bool SPLIT>
__global__ __launch_bounds__(256) void gemm_k(GA g)
{
  constexpr int LDK = 40;  // padded LDS row stride (elems); 80B = 16B-aligned, 2-way banks
  __shared__ unsigned short sAh[BM*LDK];
  __shared__ unsigned short sBh[BN*LDK];
  __shared__ unsigned short sAl[SPLIT ? BM*LDK : 8];
  __shared__ unsigned short sBl[SPLIT ? BN*LDK : 8];

  const int bz = blockIdx.z;
  const int m0 = blockIdx.y * BM;
  const int n0 = blockIdx.x * BN;
  const int t  = threadIdx.x;
  const int lane = t & 63;
  const int wave = t >> 6;
  const int wm = (wave >> 1) * (BM/2);
  const int wn = (wave & 1) * (BN/2);
  constexpr int MT = BM/32;
  constexpr int NT = BN/32;

  const unsigned short* Ah = g.A0h + (long)bz*g.sA;
  const unsigned short* Al = g.A0l ? g.A0l + (long)bz*g.sA : nullptr;
  const unsigned short* Bh = g.Bh  + (long)bz*g.sB;
  const unsigned short* Bl = g.Bl  ? g.Bl  + (long)bz*g.sB : nullptr;

  f4v acc[MT][NT];
  #pragma unroll
  for (int i=0;i<MT;i++)
    #pragma unroll
    for (int j=0;j<NT;j++) acc[i][j] = f4v{0.f,0.f,0.f,0.f};

  const int srow = t >> 2;   // 0..63
  const int scg  = t & 3;    // 16B chunk within 32-k tile
  const bool hasAlo = SPLIT && (g.A0l != nullptr);

  for (int k0 = 0; k0 < g.K; k0 += 32) {
    __syncthreads();
    const int kc = k0 + scg*8;
    #pragma unroll
    for (int p = 0; p < BM/64; ++p) {
      const int r = srow + p*64;
      const unsigned short *sh, *sl; long off;
      if (kc < g.ksplit) { sh = Ah; sl = Al; off = (long)(m0+r)*g.lda0 + kc; }
      else               { sh = g.A1h; sl = g.A1l; off = (long)(m0+r)*g.lda1 + (kc - g.ksplit); }
      *(int4*)(&sAh[r*LDK + scg*8]) = *(const int4*)(sh + off);
      if (SPLIT && hasAlo) *(int4*)(&sAl[r*LDK + scg*8]) = *(const int4*)(sl + off);
    }
    #pragma unroll
    for (int p = 0; p < BN/64; ++p) {
      const int r = srow + p*64;
      const long off = (long)(n0+r)*g.ldb + kc;
      *(int4*)(&sBh[r*LDK + scg*8]) = *(const int4*)(Bh + off);
      if (SPLIT) *(int4*)(&sBl[r*LDK + scg*8]) = *(const int4*)(Bl + off);
    }
    __syncthreads();

    const int fr = lane & 15;
    const int fk = (lane >> 4) * 8;
    s8v af[MT], bfr[NT];
    #pragma unroll
    for (int i=0;i<MT;i++) af[i]  = *(const s8v*)(&sAh[(wm + i*16 + fr)*LDK + fk]);
    #pragma unroll
    for (int j=0;j<NT;j++) bfr[j] = *(const s8v*)(&sBh[(wn + j*16 + fr)*LDK + fk]);
    #pragma unroll
    for (int i=0;i<MT;i++)
      #pragma unroll
      for (int j=0;j<NT;j++)
        acc[i][j] = __builtin_amdgcn_mfma_f32_16x16x32_bf16(af[i], bfr[j], acc[i][j], 0,0,0);
    if (SPLIT) {
      s8v bl[NT];
      #pragma unroll
      for (int j=0;j<NT;j++) bl[j] = *(const s8v*)(&sBl[(wn + j*16 + fr)*LDK + fk]);
      #pragma unroll
      for (int i=0;i<MT;i++)
        #pragma unroll
        for (int j=0;j<NT;j++)
          acc[i][j] = __builtin_amdgcn_mfma_f32_16x16x32_bf16(af[i], bl[j], acc[i][j], 0,0,0);
      if (hasAlo) {
        s8v al[MT];
        #pragma unroll
        for (int i=0;i<MT;i++) al[i] = *(const s8v*)(&sAl[(wm + i*16 + fr)*LDK + fk]);
        #pragma unroll
        for (int i=0;i<MT;i++)
          #pragma unroll
          for (int j=0;j<NT;j++)
            acc[i][j] = __builtin_amdgcn_mfma_f32_16x16x32_bf16(al[i], bfr[j], acc[i][j], 0,0,0);
      }
    }
  }

  // epilogue
  #pragma unroll
  for (int i=0;i<MT;i++)
    #pragma unroll
    for (int j=0;j<NT;j++)
      #pragma unroll
      for (int r=0;r<4;r++) {
        const int grow = m0 + wm + i*16 + ((lane>>4)<<2) + r;
        const int gcol = n0 + wn + j*16 + (lane & 15);
        float v = g.alpha * acc[i][j][r];
        if constexpr (EPI == E_F32) {
          if (g.e0) v += g.beta * ((const float*)g.e0)[(long)bz*g.sD + (long)grow*g.ldo0 + gcol];
          ((float*)g.o0)[(long)bz*g.sO + (long)grow*g.ldo0 + gcol] = v;
        } else if constexpr (EPI == E_BF16) {
          if (g.e0) v += g.beta * b2f(((const unsigned short*)g.e0)[(long)bz*g.sD + (long)grow*g.ldo0 + gcol]);
          ((unsigned short*)g.o0)[(long)bz*g.sO + (long)grow*g.ldo0 + gcol] = f2b(v);
        } else if constexpr (EPI == E_BF16T2) {
          if (g.e0) v += g.beta * b2f(((const unsigned short*)g.e0)[(long)bz*g.sD + (long)grow*g.ldo0 + gcol]);
          unsigned short hv = f2b(v);
          ((unsigned short*)g.o0)[(long)bz*g.sO + (long)grow*g.ldo0 + gcol] = hv;
          ((unsigned short*)g.o1)[(long)bz*g.sO + (long)gcol*g.ldo1 + grow] = hv;
        } else if constexpr (EPI == E_SPLIT) {
          if (g.e0) v += g.beta * ((const float*)g.e0)[(long)bz*g.sD + (long)grow*g.ldo0 + gcol];
          if (g.o0) ((float*)g.o0)[(long)bz*g.sO + (long)grow*g.ldo0 + gcol] = v;
          unsigned short hv = f2b(v);
          unsigned short lv = f2b(v - b2f(hv));
          ((unsigned short*)g.o1)[(long)bz*g.sO + (long)grow*g.ldo0 + gcol] = hv;
          ((unsigned short*)g.o2)[(long)bz*g.sO + (long)grow*g.ldo0 + gcol] = lv;
          if (g.o3) {
            ((unsigned short*)g.o3)[(long)bz*g.sO + (long)gcol*g.ldo1 + grow] = hv;
            ((unsigned short*)g.o4)[(long)bz*g.sO + (long)gcol*g.ldo1 + grow] = lv;
          }
        } else if constexpr (EPI == E_QW) {
          unsigned short hv = f2b(v);
          ((unsigned short*)g.o0)[(long)bz*g.sO + (long)grow*g.ldo0 + gcol] = hv;
          ((unsigned short*)g.o1)[(long)bz*g.sO + (long)gcol*g.ldo1 + grow] = hv;
        } else if constexpr (EPI == E_PRE) {
          v += ((const float*)g.e0)[gcol];
          v = v > 0.f ? v : 0.f;
          ((unsigned short*)g.o0)[(long)grow*g.ldo0 + gcol] = f2b(v);
        } else if constexpr (EPI == E_GH) {
          if (gcol < 512) {
            float h = v - b2f(((const unsigned short*)g.e0)[(long)grow*g.ldE + gcol]);
            unsigned short hb = f2b(h);
            ((unsigned short*)g.o0)[(long)grow*512 + gcol] = hb;
            if (g.o2) ((unsigned short*)g.o2)[(long)grow*4096 + gcol] = hb;
          } else {
            float y = b2f(((const unsigned short*)g.e1)[(long)grow*512 + (gcol-512)]) - v;
            ((unsigned short*)g.o1)[(long)grow*4096 + (gcol-512)] = f2b(y);
          }
        } else if constexpr (EPI == E_OUT) {
          float o = 0.5f*(10.1f*((const float*)g.e0)[(long)grow*1024 + gcol] + v)
                  + ((const float*)g.e1)[gcol];
          ((float*)g.o0)[(long)grow*1024 + gcol] = o;
        }
      }
}

// ------------------------------ small kernels ------------------------------

__global__ __launch_bounds__(256) void k_sqnorm(const float* __restrict__ p, long count, float* slots){
  p += (long)blockIdx.y * count;
  float s = 0.f;
  for (long i = (long)blockIdx.x*256 + threadIdx.x; i < count; i += (long)gridDim.x*256){
    float v = p[i]; s += v*v;
  }
  #pragma unroll
  for (int o=32;o>0;o>>=1) s += __shfl_down(s, o, 64);
  __shared__ float red[4];
  if ((threadIdx.x & 63)==0) red[threadIdx.x>>6] = s;
  __syncthreads();
  if (threadIdx.x==0) atomicAdd(&slots[blockIdx.y], red[0]+red[1]+red[2]+red[3]);
}

__global__ void k_scales(const float* s2, const float* fq, const float* fr, float* sc){
  int t = threadIdx.x;
  if (t < 9){
    float v = (t==0)? fq[0] : fr[t-1];
    sc[t] = v / (sqrtf(s2[t]) + 1e-5f);
  }
}

__global__ __launch_bounds__(256) void k_build_VQ(const float* __restrict__ Fq, const float* sc,
    unsigned short* Vh, unsigned short* Vl, unsigned short* Vth, unsigned short* Vtl){
  long i = (long)blockIdx.x*256 + threadIdx.x;   // < 3072*1024
  int r = (int)(i >> 10), c = (int)(i & 1023);
  float v = sc[0] * Fq[(long)(1024+r)*1024 + c];
  unsigned short h = f2b(v), l = f2b(v - b2f(h));
  Vh[i]=h; Vl[i]=l;
  long ti = (long)c*3072 + r;
  Vth[ti]=h; Vtl[ti]=l;
}

__global__ __launch_bounds__(256) void k_build_WR(const float* __restrict__ Frr, const float* sc,
    unsigned short* Wrh, unsigned short* Wrl, unsigned short* WrTh, unsigned short* WrTl){
  long i = (long)blockIdx.x*256 + threadIdx.x; // < 7*262144
  int k = (int)(i >> 18);
  long rem = i & 262143;
  int r = (int)(rem >> 9), c = (int)(rem & 511);
  float v = sc[2+k] * Frr[(long)k*524288 + (long)r*1024 + 512 + c];
  unsigned short h=f2b(v), l=f2b(v-b2f(h));
  Wrh[i]=h; Wrl[i]=l;
  long ti = (long)k*262144 + (long)c*512 + r;
  WrTh[ti]=h; WrTl[ti]=l;
}

__global__ __launch_bounds__(256) void k_asm_MQ(const float* __restrict__ Fq, const float* sc,
    const float* __restrict__ P,
    unsigned short* Mh, unsigned short* Ml, unsigned short* Nth, unsigned short* Ntl){
  long i = (long)blockIdx.x*256 + threadIdx.x; // 1024^2
  int r = (int)(i>>10), c = (int)(i&1023);
  float s = sc[0];
  float a = s*Fq[(long)r*1024+c] - s*Fq[(long)c*1024+r] + P[i];
  float d = (r==c)?1.f:0.f;
  float m = d + a, nn = d - a;
  unsigned short h=f2b(m); Mh[i]=h; Ml[i]=f2b(m-b2f(h));
  long ti=(long)c*1024+r;
  h=f2b(nn); Nth[ti]=h; Ntl[ti]=f2b(nn-b2f(h));
}

__global__ __launch_bounds__(256) void k_asm_MR(const float* __restrict__ Fr0, const float* __restrict__ Frr,
    const float* sc, const float* __restrict__ PR,
    unsigned short* Mh, unsigned short* Ml, unsigned short* Nth, unsigned short* Ntl){
  long i = (long)blockIdx.x*256 + threadIdx.x; // 8*262144
  int k = (int)(i>>18);
  long rem = i & 262143;
  int r=(int)(rem>>9), c=(int)(rem&511);
  float a;
  if (k==0){
    float s = sc[1];
    a = s*(Fr0[(long)r*512+c] - Fr0[(long)c*512+r]);
  } else {
    float s = sc[1+k];
    const float* W = Frr + (long)(k-1)*524288;
    a = s*(W[(long)c*1024 + r] - W[(long)r*1024 + c]) + PR[(long)(k-1)*262144 + rem];
  }
  float d = (r==c)?1.f:0.f;
  float m = d+a, nn = d-a;
  unsigned short h=f2b(m); Mh[i]=h; Ml[i]=f2b(m-b2f(h));
  long ti = (long)k*262144 + (long)c*512 + r;
  h=f2b(nn); Nth[ti]=h; Ntl[ti]=f2b(nn-b2f(h));
}

__global__ __launch_bounds__(256) void k_rowabs(const float* __restrict__ T, int n, float* outmax){
  const float* row = T + (long)blockIdx.y*n*n + (long)blockIdx.x*n;
  float s=0.f;
  for (int i=threadIdx.x;i<n;i+=256) s += fabsf(row[i]);
  #pragma unroll
  for (int o=32;o>0;o>>=1) s += __shfl_down(s,o,64);
  __shared__ float red[4];
  if ((threadIdx.x&63)==0) red[threadIdx.x>>6]=s;
  __syncthreads();
  if (threadIdx.x==0){
    float tot = red[0]+red[1]+red[2]+red[3];
    atomicMax((unsigned int*)&outmax[blockIdx.y], __float_as_uint(tot));
  }
}

__global__ void k_makec(const float* bmax, float* cvl){
  int t=threadIdx.x;
  if (t<9){
    float bnd = sqrtf(fmaxf(bmax[t], 1.f));   // >= sigma_max^2
    cvl[t] = 1.9f/(1.f + bnd);
  }
}

__global__ __launch_bounds__(256) void k_initX(const unsigned short* __restrict__ Mh, const float* c,
    unsigned short* Xh, unsigned short* Xth, int ln, long per){
  long i = (long)blockIdx.x*256 + threadIdx.x;
  long b = i/per; long rem = i - b*per;
  int n = 1<<ln;
  int r = (int)(rem>>ln), cj = (int)(rem & (n-1));
  float cc = c[b];
  Xh[i]  = f2b(cc * b2f(Mh[b*per + (long)cj*n + r]));  // X0 = c*M^T
  Xth[i] = f2b(cc * b2f(Mh[i]));                        // X0^T = c*M
}

__global__ __launch_bounds__(256) void k_promote(const unsigned short* __restrict__ Xh, float* Xf,
    unsigned short* Xl, unsigned short* Xtl, long n){
  long i = (long)blockIdx.x*256 + threadIdx.x;
  Xf[i] = b2f(Xh[i]);
  Xl[i] = 0; Xtl[i] = 0;
}

__global__ __launch_bounds__(256) void k_f2bf(const float* __restrict__ in, unsigned short* outp, long n){
  long i = (long)blockIdx.x*256 + threadIdx.x;
  outp[i] = f2b(in[i]);
}

// ------------------------------ host driver -------------------------------

extern "C" void kernel_launch(void* const* d_in, const int* in_sizes, int n_in,
                              void* d_out, int out_size, void* d_ws, size_t ws_size,
                              hipStream_t stream)
{
  (void)in_sizes; (void)n_in; (void)out_size; (void)ws_size;
  const float* x   = (const float*)d_in[0];
  const float* Fq  = (const float*)d_in[1];
  const float* fqp = (const float*)d_in[2];
  const float* by  = (const float*)d_in[3];
  const float* Fr0 = (const float*)d_in[4];
  const float* Frr = (const float*)d_in[5];
  const float* frp = (const float*)d_in[6];
  const float* bp  = (const float*)d_in[7];
  float* out = (float*)d_out;

  const float SQG = sqrtf(10.0f - 0.1f);
  const float SQ2 = sqrtf(2.0f);

  char* base = (char*)d_ws;
  size_t off = 0;
  auto alloc = [&](size_t bytes)->char*{
    char* p = base + off; off = (off + bytes + 255) & ~(size_t)255; return p;
  };

  // ---- persistent ----
  unsigned short* Qb  = (unsigned short*)alloc(4096l*1024*2);
  unsigned short* QTb = (unsigned short*)alloc(1024l*4096*2);
  unsigned short* RK  = (unsigned short*)alloc(8l*512*1024*2);   // Rs[k], 512x1024 each
  unsigned short* RKT = (unsigned short*)alloc(8l*1024*512*2);   // Rs[k]^T
  unsigned short* xbf = (unsigned short*)alloc(8192l*1024*2);
  float* scal = (float*)alloc(256*4);
  float* s2   = scal;        // 9 squared norms
  float* bmax = scal + 16;   // 9 row-sum maxima
  float* cvl  = scal + 32;   // 9 NS scalings
  float* sc   = scal + 48;   // 9 cayley scales

  const size_t scratch0 = off;
  // ---- setup scratch (dead before main path; later overlaid) ----
  unsigned short* Vh   = (unsigned short*)alloc(3072l*1024*2);
  unsigned short* Vl   = (unsigned short*)alloc(3072l*1024*2);
  unsigned short* Vth  = (unsigned short*)alloc(1024l*3072*2);
  unsigned short* Vtl  = (unsigned short*)alloc(1024l*3072*2);
  float* PQ            = (float*)alloc(1024l*1024*4);
  unsigned short* MQh  = (unsigned short*)alloc(1024l*1024*2);
  unsigned short* MQl  = (unsigned short*)alloc(1024l*1024*2);
  unsigned short* NQth = (unsigned short*)alloc(1024l*1024*2);
  unsigned short* NQtl = (unsigned short*)alloc(1024l*1024*2);
  unsigned short* TQ   = (unsigned short*)alloc(1024l*1024*2);
  float* T2Q           = (float*)alloc(1024l*1024*4);
  float* QXf[2]; unsigned short *QXh[2], *QXl[2], *QXth[2], *QXtl[2];
  for (int s=0;s<2;s++){
    QXf[s]=(float*)alloc(1024l*1024*4);
    QXh[s]=(unsigned short*)alloc(1024l*1024*2);
    QXl[s]=(unsigned short*)alloc(1024l*1024*2);
    QXth[s]=(unsigned short*)alloc(1024l*1024*2);
    QXtl[s]=(unsigned short*)alloc(1024l*1024*2);
  }
  unsigned short* QYh = (unsigned short*)alloc(1024l*1024*2);
  unsigned short* QYl = (unsigned short*)alloc(1024l*1024*2);
  unsigned short* Wrh  = (unsigned short*)alloc(7l*262144*2);
  unsigned short* Wrl  = (unsigned short*)alloc(7l*262144*2);
  unsigned short* WrTh = (unsigned short*)alloc(7l*262144*2);
  unsigned short* WrTl = (unsigned short*)alloc(7l*262144*2);
  float* PR            = (float*)alloc(7l*262144*4);
  unsigned short* MRh  = (unsigned short*)alloc(8l*262144*2);
  unsigned short* MRl  = (unsigned short*)alloc(8l*262144*2);
  unsigned short* NRth = (unsigned short*)alloc(8l*262144*2);
  unsigned short* NRtl = (unsigned short*)alloc(8l*262144*2);
  unsigned short* TR   = (unsigned short*)alloc(8l*262144*2);
  float* T2R           = (float*)alloc(8l*262144*4);
  float* RXf[2]; unsigned short *RXh[2], *RXl[2], *RXth[2], *RXtl[2];
  for (int s=0;s<2;s++){
    RXf[s]=(float*)alloc(8l*262144*4);
    RXh[s]=(unsigned short*)alloc(8l*262144*2);
    RXl[s]=(unsigned short*)alloc(8l*262144*2);
    RXth[s]=(unsigned short*)alloc(8l*262144*2);
    RXtl[s]=(unsigned short*)alloc(8l*262144*2);
  }
  unsigned short* RYh = (unsigned short*)alloc(8l*262144*2);
  unsigned short* RYl = (unsigned short*)alloc(8l*262144*2);

  dim3 B256(256);

  // ---- phase 0: norms & scales ----
  (void)hipMemsetAsync(scal, 0, 256*4, stream);
  k_sqnorm<<<dim3(64,1),B256,0,stream>>>(Fq,  4194304l, s2+0);
  k_sqnorm<<<dim3(64,1),B256,0,stream>>>(Fr0, 262144l,  s2+1);
  k_sqnorm<<<dim3(32,7),B256,0,stream>>>(Frr, 524288l,  s2+2);
  k_scales<<<1,16,0,stream>>>(s2, fqp, frp, sc);

  // ---- phase 1: build V / Wr (scaled, hi/lo) ----
  k_build_VQ<<<12288,B256,0,stream>>>(Fq, sc, Vh, Vl, Vth, Vtl);
  k_build_WR<<<7168,B256,0,stream>>>(Frr, sc, Wrh, Wrl, WrTh, WrTl);

  // PQ = V^T V  (split)
  { GA g{}; g.ksplit=1<<30; g.A0h=Vth; g.A0l=Vtl; g.lda0=3072;
    g.Bh=Vth; g.Bl=Vtl; g.ldb=3072; g.K=3072; g.alpha=1.f;
    g.o0=PQ; g.ldo0=1024;
    gemm_k<64,64,E_F32,true><<<dim3(16,16,1),B256,0,stream>>>(g); }
  // PR_k = Wr Wr^T (batch 7, split)
  { GA g{}; g.ksplit=1<<30; g.A0h=Wrh; g.A0l=Wrl; g.lda0=512; g.sA=262144;
    g.Bh=Wrh; g.Bl=Wrl; g.ldb=512; g.sB=262144; g.K=512; g.alpha=1.f;
    g.o0=PR; g.ldo0=512; g.sO=262144;
    gemm_k<64,64,E_F32,true><<<dim3(8,8,7),B256,0,stream>>>(g); }

  // ---- phase 2: assemble M = I + A, N^T (hi/lo) ----
  k_asm_MQ<<<4096,B256,0,stream>>>(Fq, sc, PQ, MQh, MQl, NQth, NQtl);
  k_asm_MR<<<8192,B256,0,stream>>>(Fr0, Frr, sc, PR, MRh, MRl, NRth, NRtl);

  // ---- phase 3: sigma_max bound: bnd = sqrt(||(M M^T)^2||_inf) ----
  { GA g{}; g.ksplit=1<<30; g.A0h=MQh; g.lda0=1024; g.Bh=MQh; g.ldb=1024; g.K=1024; g.alpha=1.f;
    g.o0=TQ; g.ldo0=1024;
    gemm_k<64,64,E_BF16,false><<<dim3(16,16,1),B256,0,stream>>>(g); }
  { GA g{}; g.ksplit=1<<30; g.A0h=TQ; g.lda0=1024; g.Bh=TQ; g.ldb=1024; g.K=1024; g.alpha=1.f;
    g.o0=T2Q; g.ldo0=1024;
    gemm_k<64,64,E_F32,false><<<dim3(16,16,1),B256,0,stream>>>(g); }
  { GA g{}; g.ksplit=1<<30; g.A0h=MRh; g.lda0=512; g.sA=262144; g.Bh=MRh; g.ldb=512; g.sB=262144;
    g.K=512; g.alpha=1.f; g.o0=TR; g.ldo0=512; g.sO=262144;
    gemm_k<64,64,E_BF16,false><<<dim3(8,8,8),B256,0,stream>>>(g); }
  { GA g{}; g.ksplit=1<<30; g.A0h=TR; g.lda0=512; g.sA=262144; g.Bh=TR; g.ldb=512; g.sB=262144;
    g.K=512; g.alpha=1.f; g.o0=T2R; g.ldo0=512; g.sO=262144;
    gemm_k<64,64,E_F32,false><<<dim3(8,8,8),B256,0,stream>>>(g); }
  k_rowabs<<<dim3(1024,1),B256,0,stream>>>(T2Q, 1024, bmax+0);
  k_rowabs<<<dim3(512,8),B256,0,stream>>>(T2R, 512, bmax+1);
  k_makec<<<1,16,0,stream>>>(bmax, cvl);
  k_initX<<<4096,B256,0,stream>>>(MQh, cvl+0, QXh[0], QXth[0], 10, 1048576l);
  k_initX<<<8192,B256,0,stream>>>(MRh, cvl+1, RXh[0], RXth[0], 9, 262144l);

  // ---- phase 4: Newton-Schulz, bf16 phase (10 iters) ----
  int cur = 0;
  for (int it=0; it<10; ++it){
    int nxt = cur^1;
    { GA g{}; g.ksplit=1<<30; g.A0h=QXth[cur]; g.lda0=1024; g.Bh=MQh; g.ldb=1024; g.K=1024;
      g.alpha=1.f; g.o0=QYh; g.ldo0=1024;
      gemm_k<64,64,E_BF16,false><<<dim3(16,16,1),B256,0,stream>>>(g); }
    { GA g{}; g.ksplit=1<<30; g.A0h=RXth[cur]; g.lda0=512; g.sA=262144; g.Bh=MRh; g.ldb=512; g.sB=262144;
      g.K=512; g.alpha=1.f; g.o0=RYh; g.ldo0=512; g.sO=262144;
      gemm_k<64,64,E_BF16,false><<<dim3(8,8,8),B256,0,stream>>>(g); }
    { GA g{}; g.ksplit=1<<30; g.A0h=QXh[cur]; g.lda0=1024; g.Bh=QYh; g.ldb=1024; g.K=1024;
      g.alpha=-1.f; g.beta=2.f; g.e0=QXh[cur];
      g.o0=QXh[nxt]; g.o1=QXth[nxt]; g.ldo0=1024; g.ldo1=1024;
      gemm_k<64,64,E_BF16T2,false><<<dim3(16,16,1),B256,0,stream>>>(g); }
    { GA g{}; g.ksplit=1<<30; g.A0h=RXh[cur]; g.lda0=512; g.sA=262144; g.Bh=RYh; g.ldb=512; g.sB=262144;
      g.K=512; g.alpha=-1.f; g.beta=2.f; g.e0=RXh[cur]; g.sD=262144;
      g.o0=RXh[nxt]; g.o1=RXth[nxt]; g.ldo0=512; g.ldo1=512; g.sO=262144;
      gemm_k<64,64,E_BF16T2,false><<<dim3(8,8,8),B256,0,stream>>>(g); }
    cur = nxt;
  } // cur == 0

  // ---- phase 5: promote + 2 split-precision NS iters ----
  k_promote<<<4096,B256,0,stream>>>(QXh[cur], QXf[cur], QXl[cur], QXtl[cur], 1048576l);
  k_promote<<<8192,B256,0,stream>>>(RXh[cur], RXf[cur], RXl[cur], RXtl[cur], 2097152l);
  for (int sit=0; sit<2; ++sit){
    int nxt = cur^1;
    { GA g{}; g.ksplit=1<<30; g.A0h=QXth[cur]; g.A0l=QXtl[cur]; g.lda0=1024;
      g.Bh=MQh; g.Bl=MQl; g.ldb=1024; g.K=1024; g.alpha=1.f;
      g.o1=QYh; g.o2=QYl; g.ldo0=1024;
      gemm_k<64,64,E_SPLIT,true><<<dim3(16,16,1),B256,0,stream>>>(g); }
    { GA g{}; g.ksplit=1<<30; g.A0h=RXth[cur]; g.A0l=RXtl[cur]; g.lda0=512; g.sA=262144;
      g.Bh=MRh; g.Bl=MRl; g.ldb=512; g.sB=262144; g.K=512; g.alpha=1.f;
      g.o1=RYh; g.o2=RYl; g.ldo0=512; g.sO=262144;
      gemm_k<64,64,E_SPLIT,true><<<dim3(8,8,8),B256,0,stream>>>(g); }
    { GA g{}; g.ksplit=1<<30; g.A0h=QXh[cur]; g.A0l=QXl[cur]; g.lda0=1024;
      g.Bh=QYh; g.Bl=QYl; g.ldb=1024; g.K=1024;
      g.alpha=-1.f; g.beta=2.f; g.e0=QXf[cur];
      g.o0=QXf[nxt]; g.o1=QXh[nxt]; g.o2=QXl[nxt]; g.o3=QXth[nxt]; g.o4=QXtl[nxt];
      g.ldo0=1024; g.ldo1=1024;
      gemm_k<64,64,E_SPLIT,true><<<dim3(16,16,1),B256,0,stream>>>(g); }
    { GA g{}; g.ksplit=1<<30; g.A0h=RXh[cur]; g.A0l=RXl[cur]; g.lda0=512; g.sA=262144;
      g.Bh=RYh; g.Bl=RYl; g.ldb=512; g.sB=262144; g.K=512;
      g.alpha=-1.f; g.beta=2.f; g.e0=RXf[cur]; g.sD=262144;
      g.o0=RXf[nxt]; g.o1=RXh[nxt]; g.o2=RXl[nxt]; g.o3=RXth[nxt]; g.o4=RXtl[nxt];
      g.ldo0=512; g.ldo1=512; g.sO=262144;
      gemm_k<64,64,E_SPLIT,true><<<dim3(8,8,8),B256,0,stream>>>(g); }
    cur = nxt;
  } // cur == 0 : final G = set 0

  // ---- phase 6: build Q / Q^T and R / R^T (bf16) ----
  { GA g{}; g.ksplit=1<<30; g.A0h=QXh[cur]; g.A0l=QXl[cur]; g.lda0=1024;        // top = G*N
    g.Bh=NQth; g.Bl=NQtl; g.ldb=1024; g.K=1024; g.alpha=1.f;
    g.o0=Qb; g.ldo0=1024; g.o1=QTb; g.ldo1=4096;
    gemm_k<64,64,E_QW,true><<<dim3(16,16,1),B256,0,stream>>>(g); }
  { GA g{}; g.ksplit=1<<30; g.A0h=Vh; g.A0l=Vl; g.lda0=1024;                    // bottom = -2 V G
    g.Bh=QXth[cur]; g.Bl=QXtl[cur]; g.ldb=1024; g.K=1024; g.alpha=-2.f;
    g.o0=Qb + 1024l*1024; g.ldo0=1024; g.o1=QTb + 1024; g.ldo1=4096;
    gemm_k<64,64,E_QW,true><<<dim3(16,48,1),B256,0,stream>>>(g); }
  { GA g{}; g.ksplit=1<<30; g.A0h=RXh[cur]; g.A0l=RXl[cur]; g.lda0=512; g.sA=262144;  // T1 = G*N
    g.Bh=NRth; g.Bl=NRtl; g.ldb=512; g.sB=262144; g.K=512; g.alpha=1.f;
    g.o0=RKT; g.ldo0=512; g.o1=RK; g.ldo1=1024; g.sO=524288;
    gemm_k<64,64,E_QW,true><<<dim3(8,8,8),B256,0,stream>>>(g); }
  { GA g{}; g.ksplit=1<<30; g.A0h=WrTh; g.A0l=WrTl; g.lda0=512; g.sA=262144;    // T2 = -2 Wr^T G
    g.Bh=RXth[cur]+262144; g.Bl=RXtl[cur]+262144; g.ldb=512; g.sB=262144; g.K=512; g.alpha=-2.f;
    g.o0=RKT + 524288 + 262144; g.ldo0=512; g.o1=RK + 524288 + 512; g.ldo1=1024; g.sO=524288;
    gemm_k<64,64,E_QW,true><<<dim3(8,8,7),B256,0,stream>>>(g); }

  // ---- main-path overlay buffers (alias setup scratch; stream-ordered) ----
  off = scratch0;
  unsigned short* xh  = (unsigned short*)alloc(8192l*4096*2);
  unsigned short* yh  = (unsigned short*)alloc(8192l*4096*2);
  unsigned short* pre = (unsigned short*)alloc(8192l*512*2);
  unsigned short* h0  = (unsigned short*)alloc(8192l*512*2);
  unsigned short* h1  = (unsigned short*)alloc(8192l*512*2);

  // ---- phase 7: main chain ----
  k_f2bf<<<32768,B256,0,stream>>>(x, xbf, 8388608l);
  { GA g{}; g.ksplit=1<<30; g.A0h=xbf; g.lda0=1024; g.Bh=Qb; g.ldb=1024; g.K=1024; g.alpha=SQG;
    g.o0=xh; g.ldo0=4096;
    gemm_k<128,128,E_BF16,false><<<dim3(32,64,1),B256,0,stream>>>(g); }

  for (int k=0;k<8;++k){
    unsigned short* hprev = (k==0)? nullptr : (((k-1)&1) ? h1 : h0);
    unsigned short* hnew  = (k&1) ? h1 : h0;
    // pre = relu(sqrt2 * [xk|h] @ R^T + b_k)
    { GA g{}; g.A0h = xh + (long)k*512; g.lda0=4096; g.ksplit=512;
      g.A1h = hprev; g.lda1=512;
      if (k==0){ g.Bh=RKT; g.ldb=512; } else { g.Bh=RK + (long)k*524288; g.ldb=1024; }
      g.K = (k==0)?512:1024; g.alpha=SQ2;
      g.e0 = bp + (long)k*512;
      g.o0 = pre; g.ldo0=512;
      gemm_k<128,128,E_PRE,false><<<dim3(4,64,1),B256,0,stream>>>(g); }
    // gh = sqrt2 * pre @ R ; h = gh[:, :512]-xk ; y = hprev - gh[:, 512:]
    { GA g{}; g.ksplit=1<<30; g.A0h=pre; g.lda0=512;
      if (k==0){ g.Bh=RK; g.ldb=1024; } else { g.Bh=RKT + (long)k*524288; g.ldb=512; }
      g.K=512; g.alpha=SQ2;
      g.e0 = xh + (long)k*512; g.ldE=4096;
      g.e1 = hprev;
      g.o0 = hnew;
      g.o1 = (k>=1)? (void*)(yh + (long)(k-1)*512) : nullptr;
      g.o2 = (k==7)? (void*)(yh + 3584) : nullptr;
      int N = (k==0)?512:1024;
      gemm_k<128,128,E_GH,false><<<dim3(N/128,64,1),B256,0,stream>>>(g); }
  }

  // out = 0.5*(10.1*x + sqrt_gam*(yh@Q)) + by
  { GA g{}; g.ksplit=1<<30; g.A0h=yh; g.lda0=4096; g.Bh=QTb; g.ldb=4096; g.K=4096; g.alpha=SQG;
    g.e0=x; g.e1=by; g.o0=out; g.ldo0=1024;
    gemm_k<128,128,E_OUT,false><<<dim3(8,64,1),B256,0,stream>>>(g); }
}

// Round 3
// 2047.340 us; speedup vs baseline: 1.2017x; 1.2017x over previous
//
#include <hip/hip_runtime.h>
#include <math.h>

// ---------------------------------------------------------------------------
// MonLipLayer forward on MI355X.  R3: global_load_lds staging w/ XOR swizzle,
// z-fused Q+R dispatches, STABLE coupled Newton-Schulz X' = 2X - X*(MX)
// (Jacobian 0 at X=M^-1; the R2 one-sided S-form amplified asymmetry by
// ~cond per iter -> NaN).  Cayley: top = 2X - I, bottom = -2*V*X.
// All GEMMs: C = alpha * A(MxK,row) * Bt(NxK,row)^T + beta * D.
// ---------------------------------------------------------------------------

using s8v = __attribute__((ext_vector_type(8))) short;   // 8 x bf16
using f4v = __attribute__((ext_vector_type(4))) float;
typedef unsigned short ush;

#define DEV __device__ __forceinline__

DEV float b2f(ush u){ union{unsigned int i; float f;} v; v.i = ((unsigned int)u)<<16; return v.f; }
DEV ush f2b(float f){
  union{float f; unsigned int i;} v; v.f = f;
  unsigned int u = v.i;
  return (ush)((u + 0x7fffu + ((u>>16)&1u)) >> 16);
}

typedef __attribute__((address_space(1))) void gvoid;
typedef __attribute__((address_space(3))) void lvoid;
DEV void gload16(const void* g, void* l){
  __builtin_amdgcn_global_load_lds((gvoid*)g, (lvoid*)l, 16, 0, 0);
}

struct GA {
  const ush *A0h, *A0l; long lda0;
  const ush *A1h, *A1l; long lda1; int ksplit;
  const ush *Bh, *Bl; long ldb;
  int K, M, N;
  float alpha, beta;
  long sA, sB, sO, sD;
  void *o0,*o1,*o2,*o3,*o4;
  const void *e0,*e1;
  long ldo0, ldo1, ldE;
};

enum { E_F32=0, E_BF16=1, E_BF16T2=2, E_SPLIT=3, E_QW=4, E_PRE=5, E_GH=6, E_OUT=7 };

template<int BM, int BN, int EPI, bool SPLIT>
__global__ __launch_bounds__(256) void gemm_k(GA gq, GA gr, int zsplit)
{
  // LDS: unpadded 32-elem (64B) rows; chunk position = chunk ^ ((row>>1)&3)
  __shared__ ush sAh[BM*32];
  __shared__ ush sBh[BN*32];
  __shared__ ush sAl[SPLIT ? BM*32 : 8];
  __shared__ ush sBl[SPLIT ? BN*32 : 8];

  GA g; int bz;
  if ((int)blockIdx.z < zsplit){ g = gq; bz = blockIdx.z; }
  else                         { g = gr; bz = blockIdx.z - zsplit; }
  const int m0 = blockIdx.y * BM;
  const int n0 = blockIdx.x * BN;
  if (m0 >= g.M || n0 >= g.N) return;

  const int t = threadIdx.x;
  const int lane = t & 63;
  const int wave = t >> 6;
  const int wm = (wave >> 1) * (BM/2);
  const int wn = (wave & 1) * (BN/2);
  constexpr int MT = BM/32;
  constexpr int NT = BN/32;

  const ush* Ah  = g.A0h + (long)bz*g.sA;
  const ush* Alp = SPLIT ? g.A0l + (long)bz*g.sA : nullptr;
  const ush* Bhp = g.Bh  + (long)bz*g.sB;
  const ush* Blp = SPLIT ? g.Bl  + (long)bz*g.sB : nullptr;

  f4v acc[MT][NT];
  #pragma unroll
  for (int i=0;i<MT;i++)
    #pragma unroll
    for (int j=0;j<NT;j++) acc[i][j] = f4v{0.f,0.f,0.f,0.f};

  const int sr  = lane >> 2;   // row within 16-row slab
  const int scg = lane & 3;    // LDS chunk position

  for (int k0 = 0; k0 < g.K; k0 += 32) {
    __syncthreads();
    #pragma unroll
    for (int p = 0; p < BM/64; ++p) {
      const int lr = wave*16 + sr + p*64;
      const int gc = scg ^ ((lr>>1)&3);
      const int kc = k0 + gc*8;
      long aoff; const ush* gp;
      if (kc < g.ksplit){ aoff = (long)(m0+lr)*g.lda0 + kc;               gp = Ah + aoff; }
      else              { aoff = (long)(m0+lr)*g.lda1 + (kc - g.ksplit);  gp = g.A1h + aoff; }
      gload16(gp, &sAh[(wave*16 + p*64)*32]);
      if (SPLIT) gload16(Alp + aoff, &sAl[(wave*16 + p*64)*32]);
    }
    #pragma unroll
    for (int p = 0; p < BN/64; ++p) {
      const int lr = wave*16 + sr + p*64;
      const int gc = scg ^ ((lr>>1)&3);
      const long boff = (long)(n0+lr)*g.ldb + k0 + gc*8;
      gload16(Bhp + boff, &sBh[(wave*16 + p*64)*32]);
      if (SPLIT) gload16(Blp + boff, &sBl[(wave*16 + p*64)*32]);
    }
    __syncthreads();

    const int fr = lane & 15;
    const int cc = lane >> 4;
    s8v af[MT], bf_[NT];
    #pragma unroll
    for (int i=0;i<MT;i++){ const int row = wm + i*16 + fr;
      af[i] = *(const s8v*)(&sAh[row*32 + ((cc ^ ((row>>1)&3))<<3)]); }
    #pragma unroll
    for (int j=0;j<NT;j++){ const int row = wn + j*16 + fr;
      bf_[j] = *(const s8v*)(&sBh[row*32 + ((cc ^ ((row>>1)&3))<<3)]); }
    #pragma unroll
    for (int i=0;i<MT;i++)
      #pragma unroll
      for (int j=0;j<NT;j++)
        acc[i][j] = __builtin_amdgcn_mfma_f32_16x16x32_bf16(af[i], bf_[j], acc[i][j], 0,0,0);
    if (SPLIT) {
      s8v al2[MT], bl2[NT];
      #pragma unroll
      for (int j=0;j<NT;j++){ const int row = wn + j*16 + fr;
        bl2[j] = *(const s8v*)(&sBl[row*32 + ((cc ^ ((row>>1)&3))<<3)]); }
      #pragma unroll
      for (int i=0;i<MT;i++){ const int row = wm + i*16 + fr;
        al2[i] = *(const s8v*)(&sAl[row*32 + ((cc ^ ((row>>1)&3))<<3)]); }
      #pragma unroll
      for (int i=0;i<MT;i++)
        #pragma unroll
        for (int j=0;j<NT;j++)
          acc[i][j] = __builtin_amdgcn_mfma_f32_16x16x32_bf16(af[i], bl2[j], acc[i][j], 0,0,0);
      #pragma unroll
      for (int i=0;i<MT;i++)
        #pragma unroll
        for (int j=0;j<NT;j++)
          acc[i][j] = __builtin_amdgcn_mfma_f32_16x16x32_bf16(al2[i], bf_[j], acc[i][j], 0,0,0);
    }
  }

  // epilogue
  #pragma unroll
  for (int i=0;i<MT;i++)
    #pragma unroll
    for (int j=0;j<NT;j++)
      #pragma unroll
      for (int r=0;r<4;r++) {
        const int grow = m0 + wm + i*16 + ((lane>>4)<<2) + r;
        const int gcol = n0 + wn + j*16 + (lane & 15);
        float v = g.alpha * acc[i][j][r];
        if constexpr (EPI == E_F32) {
          if (g.e0) v += g.beta * ((const float*)g.e0)[(long)bz*g.sD + (long)grow*g.ldo0 + gcol];
          ((float*)g.o0)[(long)bz*g.sO + (long)grow*g.ldo0 + gcol] = v;
        } else if constexpr (EPI == E_BF16) {
          if (g.e0) v += g.beta * b2f(((const ush*)g.e0)[(long)bz*g.sD + (long)grow*g.ldo0 + gcol]);
          ((ush*)g.o0)[(long)bz*g.sO + (long)grow*g.ldo0 + gcol] = f2b(v);
        } else if constexpr (EPI == E_BF16T2) {
          if (g.e0) v += g.beta * b2f(((const ush*)g.e0)[(long)bz*g.sD + (long)grow*g.ldo0 + gcol]);
          ush hv = f2b(v);
          ((ush*)g.o0)[(long)bz*g.sO + (long)grow*g.ldo0 + gcol] = hv;
          ((ush*)g.o1)[(long)bz*g.sO + (long)gcol*g.ldo1 + grow] = hv;
        } else if constexpr (EPI == E_SPLIT) {
          if (g.e0) v += g.beta * ((const float*)g.e0)[(long)bz*g.sD + (long)grow*g.ldo0 + gcol];
          if (g.o0) ((float*)g.o0)[(long)bz*g.sO + (long)grow*g.ldo0 + gcol] = v;
          ush hv = f2b(v);
          ush lv = f2b(v - b2f(hv));
          ((ush*)g.o1)[(long)bz*g.sO + (long)grow*g.ldo0 + gcol] = hv;
          ((ush*)g.o2)[(long)bz*g.sO + (long)grow*g.ldo0 + gcol] = lv;
          if (g.o3) {
            ((ush*)g.o3)[(long)bz*g.sO + (long)gcol*g.ldo1 + grow] = hv;
            ((ush*)g.o4)[(long)bz*g.sO + (long)gcol*g.ldo1 + grow] = lv;
          }
        } else if constexpr (EPI == E_QW) {
          ush hv = f2b(v);
          ((ush*)g.o0)[(long)bz*g.sO + (long)grow*g.ldo0 + gcol] = hv;
          ((ush*)g.o1)[(long)bz*g.sO + (long)gcol*g.ldo1 + grow] = hv;
        } else if constexpr (EPI == E_PRE) {
          v += ((const float*)g.e0)[gcol];
          v = v > 0.f ? v : 0.f;
          ((ush*)g.o0)[(long)grow*g.ldo0 + gcol] = f2b(v);
        } else if constexpr (EPI == E_GH) {
          if (gcol < 512) {
            float h = v - b2f(((const ush*)g.e0)[(long)grow*g.ldE + gcol]);
            ush hb = f2b(h);
            ((ush*)g.o0)[(long)grow*512 + gcol] = hb;
            if (g.o2) ((ush*)g.o2)[(long)grow*4096 + gcol] = hb;
          } else {
            float y = b2f(((const ush*)g.e1)[(long)grow*512 + (gcol-512)]) - v;
            ((ush*)g.o1)[(long)grow*4096 + (gcol-512)] = f2b(y);
          }
        } else if constexpr (EPI == E_OUT) {
          float o = 0.5f*(10.1f*((const float*)g.e0)[(long)grow*1024 + gcol] + v)
                  + ((const float*)g.e1)[gcol];
          ((float*)g.o0)[(long)grow*1024 + gcol] = o;
        }
      }
}

// ------------------------------ small kernels ------------------------------

__global__ __launch_bounds__(256) void k_norms(const float* __restrict__ Fq,
    const float* __restrict__ Fr0, const float* __restrict__ Frr, float* s2){
  const int y = blockIdx.y;
  const float* p; long cnt;
  if (y==0){ p=Fq; cnt=4194304l; }
  else if (y==1){ p=Fr0; cnt=262144l; }
  else { p=Frr + (long)(y-2)*524288; cnt=524288l; }
  float s = 0.f;
  for (long i = (long)blockIdx.x*256 + threadIdx.x; i < cnt; i += (long)gridDim.x*256){
    float v = p[i]; s += v*v;
  }
  #pragma unroll
  for (int o=32;o>0;o>>=1) s += __shfl_down(s, o, 64);
  __shared__ float red[4];
  if ((threadIdx.x & 63)==0) red[threadIdx.x>>6] = s;
  __syncthreads();
  if (threadIdx.x==0) atomicAdd(&s2[y], red[0]+red[1]+red[2]+red[3]);
}

__global__ void k_scales(const float* s2, const float* fq, const float* fr, float* sc){
  int t = threadIdx.x;
  if (t < 9){
    float v = (t==0)? fq[0] : fr[t-1];
    sc[t] = v / (sqrtf(s2[t]) + 1e-5f);
  }
}

__global__ __launch_bounds__(256) void k_build(const float* __restrict__ Fq,
    const float* __restrict__ Frr, const float* sc,
    ush* Vh, ush* Vl, ush* Vth, ush* Vtl,
    ush* Wrh, ush* Wrl, ush* WrTh, ush* WrTl){
  long i = (long)blockIdx.x*256 + threadIdx.x;
  if (i < 3145728l){
    int r = (int)(i >> 10), c = (int)(i & 1023);
    float v = sc[0] * Fq[(long)(1024+r)*1024 + c];
    ush h = f2b(v), l = f2b(v - b2f(h));
    Vh[i]=h; Vl[i]=l;
    long ti = (long)c*3072 + r;
    Vth[ti]=h; Vtl[ti]=l;
  } else {
    long j = i - 3145728l;
    int k = (int)(j >> 18);
    long rem = j & 262143;
    int r = (int)(rem >> 9), c = (int)(rem & 511);
    float v = sc[2+k] * Frr[(long)k*524288 + (long)r*1024 + 512 + c];
    ush h=f2b(v), l=f2b(v-b2f(h));
    Wrh[j]=h; Wrl[j]=l;
    long ti = (long)k*262144 + (long)c*512 + r;
    WrTh[ti]=h; WrTl[ti]=l;
  }
}

// M = I + A (hi/lo) and M^T (hi/lo).  Q block then 8 R batches.
__global__ __launch_bounds__(256) void k_asm(const float* __restrict__ Fq,
    const float* __restrict__ Fr0, const float* __restrict__ Frr,
    const float* sc, const float* __restrict__ PP,
    ush* Mh, ush* Ml, ush* MTh, ush* MTl){
  long i = (long)blockIdx.x*256 + threadIdx.x;
  float a; int r, c; long tidx;
  if (i < 1048576l){
    r = (int)(i>>10); c = (int)(i&1023);
    float s = sc[0];
    a = s*Fq[(long)r*1024+c] - s*Fq[(long)c*1024+r] + PP[i];
    tidx = (long)c*1024 + r;
  } else {
    long j = i - 1048576l;
    int b = (int)(j>>18);
    long rem = j & 262143;
    r = (int)(rem>>9); c = (int)(rem&511);
    if (b==0){
      float s = sc[1];
      a = s*(Fr0[(long)r*512+c] - Fr0[(long)c*512+r]);
    } else {
      float s = sc[1+b];
      const float* W = Frr + (long)(b-1)*524288;
      a = s*(W[(long)c*1024 + r] - W[(long)r*1024 + c]) + PP[1048576l + (long)(b-1)*262144 + rem];
    }
    tidx = 1048576l + (long)b*262144 + (long)c*512 + r;
  }
  float m = ((r==c)?1.f:0.f) + a;
  ush h=f2b(m), l=f2b(m-b2f(h));
  Mh[i]=h; Ml[i]=l;
  MTh[tidx]=h; MTl[tidx]=l;
}

__global__ __launch_bounds__(256) void k_rowabs(const float* __restrict__ T2, float* bmax){
  const int y = blockIdx.y;
  const float* row; int n;
  if (y==0){ row = T2 + (long)blockIdx.x*1024; n = 1024; }
  else { if (blockIdx.x >= 512) return;
         row = T2 + 1048576l + (long)(y-1)*262144 + (long)blockIdx.x*512; n = 512; }
  float s=0.f;
  for (int i=threadIdx.x;i<n;i+=256) s += fabsf(row[i]);
  #pragma unroll
  for (int o=32;o>0;o>>=1) s += __shfl_down(s,o,64);
  __shared__ float red[4];
  if ((threadIdx.x&63)==0) red[threadIdx.x>>6]=s;
  __syncthreads();
  if (threadIdx.x==0){
    float tot = red[0]+red[1]+red[2]+red[3];
    atomicMax((unsigned int*)&bmax[y], __float_as_uint(tot));
  }
}

__global__ void k_makec(const float* bmax, float* cvl){
  int t=threadIdx.x;
  if (t<9){
    float bnd = sqrtf(fmaxf(bmax[t], 1.f));   // >= sigma_max(M)^2
    cvl[t] = 1.9f/(1.f + bnd);
  }
}

// X0 = c*M^T, X0^T = c*M  (both via linear reads of MT / M)
__global__ __launch_bounds__(256) void k_initX(const ush* __restrict__ Mh,
    const ush* __restrict__ MTh, const float* cvl, ush* Xh, ush* XTh){
  long i = (long)blockIdx.x*256 + threadIdx.x;
  int b = (i < 1048576l) ? 0 : 1 + (int)((i - 1048576l) >> 18);
  float c = cvl[b];
  Xh[i]  = f2b(c * b2f(MTh[i]));
  XTh[i] = f2b(c * b2f(Mh[i]));
}

__global__ __launch_bounds__(256) void k_promote(const ush* __restrict__ Xh,
    float* Xf, ush* Xl, ush* XTl){
  long i = (long)blockIdx.x*256 + threadIdx.x;
  Xf[i] = b2f(Xh[i]);
  Xl[i] = 0; XTl[i] = 0;
}

// tops: Q_top = 2X - I ; R_top = 2X' - I  (value + transposed copy)
__global__ __launch_bounds__(256) void k_top(const ush* __restrict__ Xh, const ush* __restrict__ Xl,
    ush* Qb, ush* QTb, ush* RK, ush* RKT){
  long i = (long)blockIdx.x*256 + threadIdx.x;
  if (i < 1048576l){
    int r = (int)(i>>10), c = (int)(i&1023);
    float v = 2.f*(b2f(Xh[i]) + b2f(Xl[i])) - ((r==c)?1.f:0.f);
    ush h = f2b(v);
    Qb[(long)r*1024 + c] = h;
    QTb[(long)c*4096 + r] = h;
  } else {
    long j = i - 1048576l;
    int b = (int)(j>>18);
    long rem = j & 262143;
    int r = (int)(rem>>9), c = (int)(rem&511);
    float v = 2.f*(b2f(Xh[i]) + b2f(Xl[i])) - ((r==c)?1.f:0.f);
    ush h = f2b(v);
    RKT[(long)b*524288 + (long)r*512 + c] = h;
    RK [(long)b*524288 + (long)c*1024 + r] = h;
  }
}

__global__ __launch_bounds__(256) void k_f2bf(const float* __restrict__ in, ush* __restrict__ o){
  long i = ((long)blockIdx.x*256 + threadIdx.x)*8;
  float4 a = *(const float4*)(in+i);
  float4 b = *(const float4*)(in+i+4);
  ush u[8];
  u[0]=f2b(a.x);u[1]=f2b(a.y);u[2]=f2b(a.z);u[3]=f2b(a.w);
  u[4]=f2b(b.x);u[5]=f2b(b.y);u[6]=f2b(b.z);u[7]=f2b(b.w);
  *(int4*)(o+i) = *(const int4*)u;
}

// ------------------------------ host driver -------------------------------

static GA mk(const ush* Ah, const ush* Al, long lda,
             const ush* Bh, const ush* Bl, long ldb,
             int K, int M, int N, float alpha){
  GA g{}; g.ksplit=1<<30; g.A0h=Ah; g.A0l=Al; g.lda0=lda;
  g.Bh=Bh; g.Bl=Bl; g.ldb=ldb; g.K=K; g.M=M; g.N=N; g.alpha=alpha; g.beta=0.f;
  return g;
}

extern "C" void kernel_launch(void* const* d_in, const int* in_sizes, int n_in,
                              void* d_out, int out_size, void* d_ws, size_t ws_size,
                              hipStream_t stream)
{
  (void)in_sizes; (void)n_in; (void)out_size; (void)ws_size;
  const float* x   = (const float*)d_in[0];
  const float* Fq  = (const float*)d_in[1];
  const float* fqp = (const float*)d_in[2];
  const float* by  = (const float*)d_in[3];
  const float* Fr0 = (const float*)d_in[4];
  const float* Frr = (const float*)d_in[5];
  const float* frp = (const float*)d_in[6];
  const float* bp  = (const float*)d_in[7];
  float* out = (float*)d_out;

  const float SQG = sqrtf(10.0f - 0.1f);
  const float SQ2 = sqrtf(2.0f);
  const long UN = 3145728l;     // unified small-mat elems: Q(1024^2) + 8*R(512^2)
  const long ROFF = 1048576l, RS = 262144l;

  char* base = (char*)d_ws;
  size_t off = 0;
  auto alloc = [&](size_t bytes)->char*{
    char* p = base + off; off = (off + bytes + 255) & ~(size_t)255; return p;
  };

  // ---- persistent ----
  ush* Qb  = (ush*)alloc(4194304l*2);
  ush* QTb = (ush*)alloc(4194304l*2);
  ush* RK  = (ush*)alloc(4194304l*2);
  ush* RKT = (ush*)alloc(4194304l*2);
  ush* xbf = (ush*)alloc(8388608l*2);
  float* scal = (float*)alloc(256*4);
  float* s2   = scal;
  float* bmax = scal + 16;
  float* cvl  = scal + 32;
  float* sc   = scal + 48;

  const size_t scratch0 = off;
  // ---- setup scratch (overlaid by main path later; stream-ordered safe) ----
  ush* Vh   = (ush*)alloc(UN*2);
  ush* Vl   = (ush*)alloc(UN*2);
  ush* Vth  = (ush*)alloc(UN*2);
  ush* Vtl  = (ush*)alloc(UN*2);
  ush* Wrh  = (ush*)alloc(1835008l*2);
  ush* Wrl  = (ush*)alloc(1835008l*2);
  ush* WrTh = (ush*)alloc(1835008l*2);
  ush* WrTl = (ush*)alloc(1835008l*2);
  float* PPf = (float*)alloc(UN*4);          // V^T V / Wr Wr^T, then reused as S^2
  ush* Mh  = (ush*)alloc(UN*2);
  ush* Ml  = (ush*)alloc(UN*2);
  ush* MTh = (ush*)alloc(UN*2);
  ush* MTl = (ush*)alloc(UN*2);
  ush* Sh  = (ush*)alloc(UN*2);
  ush* XhA = (ush*)alloc(UN*2);
  ush* XhB = (ush*)alloc(UN*2);
  ush* XlA = (ush*)alloc(UN*2);
  ush* XlB = (ush*)alloc(UN*2);
  ush* XThA = (ush*)alloc(UN*2);
  ush* XThB = (ush*)alloc(UN*2);
  ush* XTlA = (ush*)alloc(UN*2);
  ush* XTlB = (ush*)alloc(UN*2);
  float* XfA = (float*)alloc(UN*4);
  float* XfB = (float*)alloc(UN*4);
  ush* Yh  = (ush*)alloc(UN*2);
  ush* Yl  = (ush*)alloc(UN*2);

  ush* Xh[2]  = {XhA, XhB};
  ush* Xl[2]  = {XlA, XlB};
  ush* XTh[2] = {XThA, XThB};
  ush* XTl[2] = {XTlA, XTlB};
  float* Xf[2] = {XfA, XfB};

  dim3 B256(256);
  GA ga{}, gr{};

  // ---- phase 0: norms & scales ----
  (void)hipMemsetAsync(scal, 0, 1024, stream);
  k_norms<<<dim3(64,9),B256,0,stream>>>(Fq, Fr0, Frr, s2);
  k_scales<<<1,16,0,stream>>>(s2, fqp, frp, sc);

  // ---- phase 1: build V / Wr ----
  k_build<<<19456,B256,0,stream>>>(Fq, Frr, sc, Vh,Vl,Vth,Vtl, Wrh,Wrl,WrTh,WrTl);

  // PQ = V^T V ; PR_k = Wr Wr^T (split) -> PPf
  ga = mk(Vth,Vtl,3072, Vth,Vtl,3072, 3072,1024,1024, 1.f); ga.o0=PPf; ga.ldo0=1024;
  gr = mk(Wrh,Wrl,512, Wrh,Wrl,512, 512,512,512, 1.f);
  gr.sA=RS; gr.sB=RS; gr.o0=PPf+ROFF; gr.sO=RS; gr.ldo0=512;
  gemm_k<64,64,E_F32,true><<<dim3(16,16,8),B256,0,stream>>>(ga,gr,1);

  // ---- phase 2: assemble M, M^T (hi/lo) ----
  k_asm<<<12288,B256,0,stream>>>(Fq, Fr0, Frr, sc, PPf, Mh,Ml,MTh,MTl);

  // ---- phase 3: bound: S = M*M^T (bf16), S^2 (f32), rowabs, c, X0 ----
  ga = mk(Mh,nullptr,1024, Mh,nullptr,1024, 1024,1024,1024, 1.f); ga.o0=Sh; ga.ldo0=1024;
  gr = mk(Mh+ROFF,nullptr,512, Mh+ROFF,nullptr,512, 512,512,512, 1.f);
  gr.sA=RS; gr.sB=RS; gr.o0=Sh+ROFF; gr.sO=RS; gr.ldo0=512;
  gemm_k<64,64,E_BF16,false><<<dim3(16,16,9),B256,0,stream>>>(ga,gr,1);

  ga = mk(Sh,nullptr,1024, Sh,nullptr,1024, 1024,1024,1024, 1.f); ga.o0=PPf; ga.ldo0=1024;
  gr = mk(Sh+ROFF,nullptr,512, Sh+ROFF,nullptr,512, 512,512,512, 1.f);
  gr.sA=RS; gr.sB=RS; gr.o0=PPf+ROFF; gr.sO=RS; gr.ldo0=512;
  gemm_k<64,64,E_F32,false><<<dim3(16,16,9),B256,0,stream>>>(ga,gr,1);
  k_rowabs<<<dim3(1024,9),B256,0,stream>>>(PPf, bmax);
  k_makec<<<1,16,0,stream>>>(bmax, cvl);
  k_initX<<<12288,B256,0,stream>>>(Mh, MTh, cvl, Xh[0], XTh[0]);

  // ---- phase 4: coupled NS bf16: Y=(MX)^T ; X' = 2X - X*Y^T  (9 iters) ----
  int cur = 0;
  for (int it=0; it<9; ++it){
    int nxt = cur^1;
    ga = mk(XTh[cur],nullptr,1024, Mh,nullptr,1024, 1024,1024,1024, 1.f); ga.o0=Yh; ga.ldo0=1024;
    gr = mk(XTh[cur]+ROFF,nullptr,512, Mh+ROFF,nullptr,512, 512,512,512, 1.f);
    gr.sA=RS; gr.sB=RS; gr.o0=Yh+ROFF; gr.sO=RS; gr.ldo0=512;
    gemm_k<64,64,E_BF16,false><<<dim3(16,16,9),B256,0,stream>>>(ga,gr,1);

    ga = mk(Xh[cur],nullptr,1024, Yh,nullptr,1024, 1024,1024,1024, -1.f);
    ga.beta=2.f; ga.e0=Xh[cur];
    ga.o0=Xh[nxt]; ga.o1=XTh[nxt]; ga.ldo0=1024; ga.ldo1=1024;
    gr = mk(Xh[cur]+ROFF,nullptr,512, Yh+ROFF,nullptr,512, 512,512,512, -1.f);
    gr.beta=2.f; gr.e0=Xh[cur]+ROFF; gr.sD=RS;
    gr.sA=RS; gr.sB=RS; gr.sO=RS;
    gr.o0=Xh[nxt]+ROFF; gr.o1=XTh[nxt]+ROFF; gr.ldo0=512; gr.ldo1=512;
    gemm_k<64,64,E_BF16T2,false><<<dim3(16,16,9),B256,0,stream>>>(ga,gr,1);
    cur = nxt;
  }

  // ---- phase 5: promote + 2 split-precision NS iters ----
  k_promote<<<12288,B256,0,stream>>>(Xh[cur], Xf[cur], Xl[cur], XTl[cur]);
  for (int it=0; it<2; ++it){
    int nxt = cur^1;
    ga = mk(XTh[cur],XTl[cur],1024, Mh,Ml,1024, 1024,1024,1024, 1.f);
    ga.o1=Yh; ga.o2=Yl; ga.ldo0=1024;
    gr = mk(XTh[cur]+ROFF,XTl[cur]+ROFF,512, Mh+ROFF,Ml+ROFF,512, 512,512,512, 1.f);
    gr.sA=RS; gr.sB=RS; gr.o1=Yh+ROFF; gr.o2=Yl+ROFF; gr.sO=RS; gr.ldo0=512;
    gemm_k<64,64,E_SPLIT,true><<<dim3(16,16,9),B256,0,stream>>>(ga,gr,1);

    ga = mk(Xh[cur],Xl[cur],1024, Yh,Yl,1024, 1024,1024,1024, -1.f);
    ga.beta=2.f; ga.e0=Xf[cur];
    ga.o0=Xf[nxt]; ga.o1=Xh[nxt]; ga.o2=Xl[nxt]; ga.o3=XTh[nxt]; ga.o4=XTl[nxt];
    ga.ldo0=1024; ga.ldo1=1024;
    gr = mk(Xh[cur]+ROFF,Xl[cur]+ROFF,512, Yh+ROFF,Yl+ROFF,512, 512,512,512, -1.f);
    gr.beta=2.f; gr.e0=Xf[cur]+ROFF; gr.sD=RS;
    gr.sA=RS; gr.sB=RS; gr.sO=RS;
    gr.o0=Xf[nxt]+ROFF; gr.o1=Xh[nxt]+ROFF; gr.o2=Xl[nxt]+ROFF;
    gr.o3=XTh[nxt]+ROFF; gr.o4=XTl[nxt]+ROFF;
    gr.ldo0=512; gr.ldo1=512;
    gemm_k<64,64,E_SPLIT,true><<<dim3(16,16,9),B256,0,stream>>>(ga,gr,1);
    cur = nxt;
  }

  // ---- phase 6: tops = 2X - I (elementwise) ; bottoms = -2*V*X ----
  k_top<<<12288,B256,0,stream>>>(Xh[cur], Xl[cur], Qb, QTb, RK, RKT);

  ga = mk(Vh,Vl,1024, XTh[cur],XTl[cur],1024, 1024,3072,1024, -2.f);
  ga.o0=Qb + 1048576l; ga.ldo0=1024; ga.o1=QTb + 1024; ga.ldo1=4096;
  gr = mk(WrTh,WrTl,512, XTh[cur]+ROFF+RS, XTl[cur]+ROFF+RS, 512, 512,512,512, -2.f);
  gr.sA=RS; gr.sB=RS; gr.sO=524288;
  gr.o0=RKT + 524288 + 262144; gr.ldo0=512;
  gr.o1=RK + 524288 + 512; gr.ldo1=1024;
  gemm_k<64,64,E_QW,true><<<dim3(16,48,8),B256,0,stream>>>(ga,gr,1);

  // ---- main-path overlay buffers (alias setup scratch; stream-ordered) ----
  off = scratch0;
  ush* xh  = (ush*)alloc(33554432l*2);
  ush* yh  = (ush*)alloc(33554432l*2);
  ush* pre = (ush*)alloc(4194304l*2);
  ush* h0  = (ush*)alloc(4194304l*2);
  ush* h1  = (ush*)alloc(4194304l*2);

  // ---- phase 7: main chain ----
  k_f2bf<<<4096,B256,0,stream>>>(x, xbf);
  ga = mk(xbf,nullptr,1024, Qb,nullptr,1024, 1024,8192,4096, SQG);
  ga.o0=xh; ga.ldo0=4096;
  gemm_k<128,128,E_BF16,false><<<dim3(32,64,1),B256,0,stream>>>(ga,ga,1);

  for (int k=0;k<8;++k){
    ush* hprev = (k==0)? nullptr : (((k-1)&1) ? h1 : h0);
    ush* hnew  = (k&1) ? h1 : h0;
    // pre = relu(sqrt2 * [xk|h] @ R^T + b_k)
    GA gp_ = mk(xh + (long)k*512, nullptr, 4096,
                (k==0)? RKT : RK + (long)k*524288, nullptr, (k==0)?512:1024,
                (k==0)?512:1024, 8192, 512, SQ2);
    gp_.ksplit = 512; gp_.A1h = hprev; gp_.lda1 = 512;
    gp_.e0 = bp + (long)k*512; gp_.o0 = pre; gp_.ldo0 = 512;
    gemm_k<128,64,E_PRE,false><<<dim3(8,64,1),B256,0,stream>>>(gp_,gp_,1);

    // gh = sqrt2 * pre @ R ; h = gh[:, :512]-xk ; y = hprev - gh[:, 512:]
    GA gg = mk(pre, nullptr, 512,
               (k==0)? RK : RKT + (long)k*524288, nullptr, (k==0)?1024:512,
               512, 8192, (k==0)?512:1024, SQ2);
    gg.e0 = xh + (long)k*512; gg.ldE = 4096;
    gg.e1 = hprev;
    gg.o0 = hnew;
    gg.o1 = (k>=1)? (void*)(yh + (long)(k-1)*512) : nullptr;
    gg.o2 = (k==7)? (void*)(yh + 3584) : nullptr;
    if (k==0) gemm_k<128,64,E_GH,false><<<dim3(8,64,1),B256,0,stream>>>(gg,gg,1);
    else      gemm_k<128,128,E_GH,false><<<dim3(8,64,1),B256,0,stream>>>(gg,gg,1);
  }

  // out = 0.5*(10.1*x + sqrt_gam*(yh@Q)) + by
  ga = mk(yh,nullptr,4096, QTb,nullptr,4096, 4096,8192,1024, SQG);
  ga.e0=x; ga.e1=by; ga.o0=out; ga.ldo0=1024;
  gemm_k<128,128,E_OUT,false><<<dim3(8,64,1),B256,0,stream>>>(ga,ga,1);
}

// Round 4
// 1758.485 us; speedup vs baseline: 1.3990x; 1.1643x over previous
//
#include <hip/hip_runtime.h>
#include <math.h>

// ---------------------------------------------------------------------------
// MonLipLayer forward on MI355X.  R4: all transposed writes go through LDS
// (64x65 staging, coalesced 32B stores) -- R3 scattered 2B stores had ~32x
// write amplification.  Supertile block swizzle for B-reuse in L2.
// Math identical to R3 (coupled NS, 9 bf16 + 2 split iters).
// All GEMMs: C = alpha * A(MxK,row) * Bt(NxK,row)^T + beta * D.
// ---------------------------------------------------------------------------

using s8v = __attribute__((ext_vector_type(8))) short;   // 8 x bf16
using f4v = __attribute__((ext_vector_type(4))) float;
typedef unsigned short ush;
typedef unsigned int uint32;

#define DEV __device__ __forceinline__

DEV float b2f(ush u){ union{unsigned int i; float f;} v; v.i = ((unsigned int)u)<<16; return v.f; }
DEV ush f2b(float f){
  union{float f; unsigned int i;} v; v.f = f;
  unsigned int u = v.i;
  return (ush)((u + 0x7fffu + ((u>>16)&1u)) >> 16);
}

typedef __attribute__((address_space(1))) void gvoid;
typedef __attribute__((address_space(3))) void lvoid;
DEV void gload16(const void* g, void* l){
  __builtin_amdgcn_global_load_lds((gvoid*)g, (lvoid*)l, 16, 0, 0);
}

DEV void st16(ush* dst, const ush* a){
  *(int4*)dst = *(const int4*)a; *(int4*)(dst+8) = *(const int4*)(a+8);
}

struct GA {
  const ush *A0h, *A0l; long lda0;
  const ush *A1h, *A1l; long lda1; int ksplit;
  const ush *Bh, *Bl; long ldb;
  int K, M, N;
  float alpha, beta;
  long sA, sB, sO, sD;
  void *o0,*o1,*o2,*o3,*o4;
  const void *e0,*e1;
  long ldo0, ldo1, ldE;
};

enum { E_F32=0, E_BF16=1, E_BF16T2=2, E_SPLIT=3, E_QW=4, E_PRE=5, E_GH=6, E_OUT=7 };

template<int BM, int BN, int EPI, bool SPLIT, bool TRX>
__global__ __launch_bounds__(256) void gemm_k(GA gq, GA gr, int zsplit)
{
  __shared__ ush sAh[BM*32];
  __shared__ ush sBh[BN*32];
  __shared__ ush sAl[SPLIT ? BM*32 : 8];
  __shared__ ush sBl[SPLIT ? BN*32 : 8];
  __shared__ uint32 tb[TRX ? 64*65 : 8];

  GA g; int bz;
  if ((int)blockIdx.z < zsplit){ g = gq; bz = blockIdx.z; }
  else                         { g = gr; bz = blockIdx.z - zsplit; }

  // supertile swizzle: groups of 8 block-rows, column-major inside a group
  const int gx = gridDim.x, gy = gridDim.y;
  const int lin = blockIdx.y*gx + blockIdx.x;
  const int per = gx*8;
  const int grp = lin / per;
  const int rem = lin - grp*per;
  int gh = gy - grp*8; if (gh > 8) gh = 8;
  const int by = grp*8 + rem % gh;
  const int bx = rem / gh;
  const int m0 = by * BM;
  const int n0 = bx * BN;
  if (m0 >= g.M || n0 >= g.N) return;

  const int t = threadIdx.x;
  const int lane = t & 63;
  const int wave = t >> 6;
  const int wm = (wave >> 1) * (BM/2);
  const int wn = (wave & 1) * (BN/2);
  constexpr int MT = BM/32;
  constexpr int NT = BN/32;

  const ush* Ah  = g.A0h + (long)bz*g.sA;
  const ush* Alp = SPLIT ? g.A0l + (long)bz*g.sA : nullptr;
  const ush* Bhp = g.Bh  + (long)bz*g.sB;
  const ush* Blp = SPLIT ? g.Bl  + (long)bz*g.sB : nullptr;

  f4v acc[MT][NT];
  #pragma unroll
  for (int i=0;i<MT;i++)
    #pragma unroll
    for (int j=0;j<NT;j++) acc[i][j] = f4v{0.f,0.f,0.f,0.f};

  const int sr  = lane >> 2;
  const int scg = lane & 3;

  for (int k0 = 0; k0 < g.K; k0 += 32) {
    __syncthreads();
    #pragma unroll
    for (int p = 0; p < BM/64; ++p) {
      const int lr = wave*16 + sr + p*64;
      const int gc = scg ^ ((lr>>1)&3);
      const int kc = k0 + gc*8;
      long aoff; const ush* gp;
      if (kc < g.ksplit){ aoff = (long)(m0+lr)*g.lda0 + kc;               gp = Ah + aoff; }
      else              { aoff = (long)(m0+lr)*g.lda1 + (kc - g.ksplit);  gp = g.A1h + aoff; }
      gload16(gp, &sAh[(wave*16 + p*64)*32]);
      if (SPLIT) gload16(Alp + aoff, &sAl[(wave*16 + p*64)*32]);
    }
    #pragma unroll
    for (int p = 0; p < BN/64; ++p) {
      const int lr = wave*16 + sr + p*64;
      const int gc = scg ^ ((lr>>1)&3);
      const long boff = (long)(n0+lr)*g.ldb + k0 + gc*8;
      gload16(Bhp + boff, &sBh[(wave*16 + p*64)*32]);
      if (SPLIT) gload16(Blp + boff, &sBl[(wave*16 + p*64)*32]);
    }
    __syncthreads();

    const int fr = lane & 15;
    const int cc = lane >> 4;
    s8v af[MT], bf_[NT];
    #pragma unroll
    for (int i=0;i<MT;i++){ const int row = wm + i*16 + fr;
      af[i] = *(const s8v*)(&sAh[row*32 + ((cc ^ ((row>>1)&3))<<3)]); }
    #pragma unroll
    for (int j=0;j<NT;j++){ const int row = wn + j*16 + fr;
      bf_[j] = *(const s8v*)(&sBh[row*32 + ((cc ^ ((row>>1)&3))<<3)]); }
    #pragma unroll
    for (int i=0;i<MT;i++)
      #pragma unroll
      for (int j=0;j<NT;j++)
        acc[i][j] = __builtin_amdgcn_mfma_f32_16x16x32_bf16(af[i], bf_[j], acc[i][j], 0,0,0);
    if (SPLIT) {
      s8v al2[MT], bl2[NT];
      #pragma unroll
      for (int j=0;j<NT;j++){ const int row = wn + j*16 + fr;
        bl2[j] = *(const s8v*)(&sBl[row*32 + ((cc ^ ((row>>1)&3))<<3)]); }
      #pragma unroll
      for (int i=0;i<MT;i++){ const int row = wm + i*16 + fr;
        al2[i] = *(const s8v*)(&sAl[row*32 + ((cc ^ ((row>>1)&3))<<3)]); }
      #pragma unroll
      for (int i=0;i<MT;i++)
        #pragma unroll
        for (int j=0;j<NT;j++)
          acc[i][j] = __builtin_amdgcn_mfma_f32_16x16x32_bf16(af[i], bl2[j], acc[i][j], 0,0,0);
      #pragma unroll
      for (int i=0;i<MT;i++)
        #pragma unroll
        for (int j=0;j<NT;j++)
          acc[i][j] = __builtin_amdgcn_mfma_f32_16x16x32_bf16(al2[i], bf_[j], acc[i][j], 0,0,0);
    }
  }

  // ---------------- epilogue: direct writes (+ LDS staging for TRX) --------
  #pragma unroll
  for (int i=0;i<MT;i++)
    #pragma unroll
    for (int j=0;j<NT;j++)
      #pragma unroll
      for (int r=0;r<4;r++) {
        const int lrow = wm + i*16 + ((lane>>4)<<2) + r;
        const int lcol = wn + j*16 + (lane & 15);
        const int grow = m0 + lrow;
        const int gcol = n0 + lcol;
        float v = g.alpha * acc[i][j][r];
        if constexpr (EPI == E_F32) {
          if (g.e0) v += g.beta * ((const float*)g.e0)[(long)bz*g.sD + (long)grow*g.ldo0 + gcol];
          ((float*)g.o0)[(long)bz*g.sO + (long)grow*g.ldo0 + gcol] = v;
        } else if constexpr (EPI == E_BF16) {
          if (g.e0) v += g.beta * b2f(((const ush*)g.e0)[(long)bz*g.sD + (long)grow*g.ldo0 + gcol]);
          ((ush*)g.o0)[(long)bz*g.sO + (long)grow*g.ldo0 + gcol] = f2b(v);
        } else if constexpr (EPI == E_BF16T2) {
          if (g.e0) v += g.beta * b2f(((const ush*)g.e0)[(long)bz*g.sD + (long)grow*g.ldo0 + gcol]);
          ush hv = f2b(v);
          ((ush*)g.o0)[(long)bz*g.sO + (long)grow*g.ldo0 + gcol] = hv;
          tb[lrow*65 + lcol] = hv;
        } else if constexpr (EPI == E_SPLIT) {
          if (g.e0) v += g.beta * ((const float*)g.e0)[(long)bz*g.sD + (long)grow*g.ldo0 + gcol];
          if (g.o0) ((float*)g.o0)[(long)bz*g.sO + (long)grow*g.ldo0 + gcol] = v;
          ush hv = f2b(v);
          ush lv = f2b(v - b2f(hv));
          ((ush*)g.o1)[(long)bz*g.sO + (long)grow*g.ldo0 + gcol] = hv;
          ((ush*)g.o2)[(long)bz*g.sO + (long)grow*g.ldo0 + gcol] = lv;
          if (TRX) tb[lrow*65 + lcol] = (uint32)hv | ((uint32)lv<<16);
        } else if constexpr (EPI == E_QW) {
          ush hv = f2b(v);
          ((ush*)g.o0)[(long)bz*g.sO + (long)grow*g.ldo0 + gcol] = hv;
          tb[lrow*65 + lcol] = hv;
        } else if constexpr (EPI == E_PRE) {
          v += ((const float*)g.e0)[gcol];
          v = v > 0.f ? v : 0.f;
          ((ush*)g.o0)[(long)grow*g.ldo0 + gcol] = f2b(v);
        } else if constexpr (EPI == E_GH) {
          if (gcol < 512) {
            float h = v - b2f(((const ush*)g.e0)[(long)grow*g.ldE + gcol]);
            ush hb = f2b(h);
            ((ush*)g.o0)[(long)grow*512 + gcol] = hb;
            if (g.o2) ((ush*)g.o2)[(long)grow*4096 + gcol] = hb;
          } else {
            float y = b2f(((const ush*)g.e1)[(long)grow*512 + (gcol-512)]) - v;
            ((ush*)g.o1)[(long)grow*4096 + (gcol-512)] = f2b(y);
          }
        } else if constexpr (EPI == E_OUT) {
          float o = 0.5f*(10.1f*((const float*)g.e0)[(long)grow*1024 + gcol] + v)
                  + ((const float*)g.e1)[gcol];
          ((float*)g.o0)[(long)grow*1024 + gcol] = o;
        }
      }

  // ---------------- transposed writes (coalesced via LDS) ------------------
  if constexpr (TRX) {
    __syncthreads();
    const int tr  = t >> 2;     // transposed row = original col
    const int seg = t & 3;
    uint32 vals[16];
    #pragma unroll
    for (int u=0;u<16;u++) vals[u] = tb[(seg*16+u)*65 + tr];
    ush hb[16] __attribute__((aligned(16)));
    ush lb[16] __attribute__((aligned(16)));
    #pragma unroll
    for (int u=0;u<16;u++){ hb[u] = (ush)(vals[u]&0xffffu); lb[u] = (ush)(vals[u]>>16); }
    const long bT = (long)bz*g.sO + (long)(n0+tr)*g.ldo1 + m0 + seg*16;
    if constexpr (EPI == E_BF16T2) {
      st16((ush*)g.o1 + bT, hb);
    } else if constexpr (EPI == E_SPLIT) {
      if (g.o3) { st16((ush*)g.o3 + bT, hb); st16((ush*)g.o4 + bT, lb); }
    } else if constexpr (EPI == E_QW) {
      st16((ush*)g.o1 + bT, hb);
    }
  }
}

// ------------------------------ small kernels ------------------------------

__global__ __launch_bounds__(256) void k_norms(const float* __restrict__ Fq,
    const float* __restrict__ Fr0, const float* __restrict__ Frr, float* s2){
  const int y = blockIdx.y;
  const float* p; long cnt;
  if (y==0){ p=Fq; cnt=4194304l; }
  else if (y==1){ p=Fr0; cnt=262144l; }
  else { p=Frr + (long)(y-2)*524288; cnt=524288l; }
  float s = 0.f;
  for (long i = (long)blockIdx.x*256 + threadIdx.x; i < cnt; i += (long)gridDim.x*256){
    float v = p[i]; s += v*v;
  }
  #pragma unroll
  for (int o=32;o>0;o>>=1) s += __shfl_down(s, o, 64);
  __shared__ float red[4];
  if ((threadIdx.x & 63)==0) red[threadIdx.x>>6] = s;
  __syncthreads();
  if (threadIdx.x==0) atomicAdd(&s2[y], red[0]+red[1]+red[2]+red[3]);
}

__global__ void k_scales(const float* s2, const float* fq, const float* fr, float* sc){
  int t = threadIdx.x;
  if (t < 9){
    float v = (t==0)? fq[0] : fr[t-1];
    sc[t] = v / (sqrtf(s2[t]) + 1e-5f);
  }
}

// tiled build of V (3072x1024, z=0) and Wr (7x512x512, z=1..7), hi/lo + transpose
__global__ __launch_bounds__(256) void k_buildT(const float* __restrict__ Fq,
    const float* __restrict__ Frr, const float* sc,
    ush* Vh, ush* Vl, ush* Vth, ush* Vtl,
    ush* Wrh, ush* Wrl, ush* WrTh, ush* WrTl){
  __shared__ uint32 tb[64*65];
  const int z = blockIdx.z;
  const int r = threadIdx.x >> 2;
  const int cs = (threadIdx.x & 3)*16;
  ush hh[16] __attribute__((aligned(16)));
  ush ll[16] __attribute__((aligned(16)));
  if (z==0){
    const long r0 = (long)blockIdx.y*64, c0 = (long)blockIdx.x*64;
    const float s = sc[0];
    const float* src = &Fq[(1024+r0+r)*1024 + c0 + cs];
    #pragma unroll
    for (int u=0;u<16;u++){
      float v = s*src[u];
      ush h = f2b(v); ush l = f2b(v - b2f(h));
      hh[u]=h; ll[u]=l;
      tb[r*65 + cs + u] = (uint32)h | ((uint32)l<<16);
    }
    st16(&Vh[(r0+r)*1024 + c0 + cs], hh);
    st16(&Vl[(r0+r)*1024 + c0 + cs], ll);
    __syncthreads();
    const int tr = threadIdx.x>>2, seg = threadIdx.x&3;
    #pragma unroll
    for (int u=0;u<16;u++){
      uint32 v = tb[(seg*16+u)*65 + tr];
      hh[u]=(ush)(v&0xffffu); ll[u]=(ush)(v>>16);
    }
    st16(&Vth[(c0+tr)*3072 + r0 + seg*16], hh);
    st16(&Vtl[(c0+tr)*3072 + r0 + seg*16], ll);
  } else {
    if (blockIdx.x>=8 || blockIdx.y>=8) return;
    const int k = z-1;
    const long r0 = (long)blockIdx.y*64, c0 = (long)blockIdx.x*64;
    const float s = sc[2+k];
    const float* src = &Frr[(long)k*524288 + (r0+r)*1024 + 512 + c0 + cs];
    #pragma unroll
    for (int u=0;u<16;u++){
      float v = s*src[u];
      ush h = f2b(v); ush l = f2b(v - b2f(h));
      hh[u]=h; ll[u]=l;
      tb[r*65 + cs + u] = (uint32)h | ((uint32)l<<16);
    }
    st16(&Wrh[(long)k*262144 + (r0+r)*512 + c0 + cs], hh);
    st16(&Wrl[(long)k*262144 + (r0+r)*512 + c0 + cs], ll);
    __syncthreads();
    const int tr = threadIdx.x>>2, seg = threadIdx.x&3;
    #pragma unroll
    for (int u=0;u<16;u++){
      uint32 v = tb[(seg*16+u)*65 + tr];
      hh[u]=(ush)(v&0xffffu); ll[u]=(ush)(v>>16);
    }
    st16(&WrTh[(long)k*262144 + (c0+tr)*512 + r0 + seg*16], hh);
    st16(&WrTl[(long)k*262144 + (c0+tr)*512 + r0 + seg*16], ll);
  }
}

// tiled assembly of M = I + A (hi/lo) and M^T: z=0 Q (16x16 tiles), z=1..8 R (8x8)
__global__ __launch_bounds__(256) void k_asmT(const float* __restrict__ Fq,
    const float* __restrict__ Fr0, const float* __restrict__ Frr,
    const float* sc, const float* __restrict__ PP,
    ush* Mh, ush* Ml, ush* MTh, ush* MTl){
  __shared__ uint32 tb[64*65];
  const int z = blockIdx.z;
  const int r = threadIdx.x >> 2;
  const int cs = (threadIdx.x & 3)*16;
  const long ROFF = 1048576l, RS = 262144l;
  long r0 = (long)blockIdx.y*64, c0 = (long)blockIdx.x*64;
  const float* dsrc; const float* msrc; const float* psrc = nullptr;
  float s; long obase; long old_; float sgn;
  if (z==0){
    s = sc[0]; sgn = 1.f;
    dsrc = &Fq[(r0+r)*1024 + c0 + cs];
    msrc = &Fq[(c0+r)*1024 + r0 + cs];
    psrc = &PP[(r0+r)*1024 + c0 + cs];
    obase = 0; old_ = 1024;
  } else {
    if (blockIdx.x>=8 || blockIdx.y>=8) return;
    const int b = z-1;
    if (b==0){
      s = sc[1]; sgn = 1.f;
      dsrc = &Fr0[(r0+r)*512 + c0 + cs];
      msrc = &Fr0[(c0+r)*512 + r0 + cs];
    } else {
      s = sc[1+b]; sgn = -1.f;   // a = s*(W[c][r]-W[r][c]) = s*(mirror-direct)
      const float* W = Frr + (long)(b-1)*524288;
      dsrc = &W[(r0+r)*1024 + c0 + cs];
      msrc = &W[(c0+r)*1024 + r0 + cs];
      psrc = &PP[ROFF + (long)(b-1)*RS + (r0+r)*512 + c0 + cs];
    }
    obase = ROFF + (long)b*RS; old_ = 512;
  }
  // stage mirror tile (float bits)
  #pragma unroll
  for (int u=0;u<16;u++) tb[r*65 + cs + u] = __float_as_uint(msrc[u]);
  __syncthreads();
  ush hh[16] __attribute__((aligned(16)));
  ush ll[16] __attribute__((aligned(16)));
  #pragma unroll
  for (int u=0;u<16;u++){
    const int c = cs + u;
    float mir = __uint_as_float(tb[c*65 + r]);
    float a = sgn * s * (dsrc[u] - mir);
    if (psrc) a += psrc[u];
    float m = ((r0 + r == c0 + c) ? 1.f : 0.f) + a;
    ush h = f2b(m); ush l = f2b(m - b2f(h));
    hh[u]=h; ll[u]=l;
  }
  st16(&Mh[obase + (r0+r)*old_ + c0 + cs], hh);
  st16(&Ml[obase + (r0+r)*old_ + c0 + cs], ll);
  __syncthreads();
  #pragma unroll
  for (int u=0;u<16;u++) tb[r*65 + cs + u] = (uint32)hh[u] | ((uint32)ll[u]<<16);
  __syncthreads();
  const int tr = threadIdx.x>>2, seg = threadIdx.x&3;
  #pragma unroll
  for (int u=0;u<16;u++){
    uint32 v = tb[(seg*16+u)*65 + tr];
    hh[u]=(ush)(v&0xffffu); ll[u]=(ush)(v>>16);
  }
  st16(&MTh[obase + (c0+tr)*old_ + r0 + seg*16], hh);
  st16(&MTl[obase + (c0+tr)*old_ + r0 + seg*16], ll);
}

__global__ __launch_bounds__(256) void k_rowabs(const float* __restrict__ T2, float* bmax){
  const int y = blockIdx.y;
  const float* row; int n;
  if (y==0){ row = T2 + (long)blockIdx.x*1024; n = 1024; }
  else { if (blockIdx.x >= 512) return;
         row = T2 + 1048576l + (long)(y-1)*262144 + (long)blockIdx.x*512; n = 512; }
  float s=0.f;
  for (int i=threadIdx.x;i<n;i+=256) s += fabsf(row[i]);
  #pragma unroll
  for (int o=32;o>0;o>>=1) s += __shfl_down(s,o,64);
  __shared__ float red[4];
  if ((threadIdx.x&63)==0) red[threadIdx.x>>6]=s;
  __syncthreads();
  if (threadIdx.x==0){
    float tot = red[0]+red[1]+red[2]+red[3];
    atomicMax((unsigned int*)&bmax[y], __float_as_uint(tot));
  }
}

__global__ void k_makec(const float* bmax, float* cvl){
  int t=threadIdx.x;
  if (t<9){
    float bnd = sqrtf(fmaxf(bmax[t], 1.f));   // >= sigma_max(M)^2
    cvl[t] = 1.9f/(1.f + bnd);
  }
}

__global__ __launch_bounds__(256) void k_initX(const ush* __restrict__ Mh,
    const ush* __restrict__ MTh, const float* cvl, ush* Xh, ush* XTh){
  long i = (long)blockIdx.x*256 + threadIdx.x;
  int b = (i < 1048576l) ? 0 : 1 + (int)((i - 1048576l) >> 18);
  float c = cvl[b];
  Xh[i]  = f2b(c * b2f(MTh[i]));
  XTh[i] = f2b(c * b2f(Mh[i]));
}

__global__ __launch_bounds__(256) void k_promote(const ush* __restrict__ Xh,
    float* Xf, ush* Xl, ush* XTl){
  long i = (long)blockIdx.x*256 + threadIdx.x;
  Xf[i] = b2f(Xh[i]);
  Xl[i] = 0; XTl[i] = 0;
}

// tops: 2X - I, tiled, value + transposed copy.  z=0 Q (16x16), z=1..8 R (8x8)
__global__ __launch_bounds__(256) void k_topT(const ush* __restrict__ Xh, const ush* __restrict__ Xl,
    ush* Qb, ush* QTb, ush* RK, ush* RKT){
  __shared__ uint32 tb[64*65];
  const int z = blockIdx.z;
  const int r = threadIdx.x >> 2;
  const int cs = (threadIdx.x & 3)*16;
  const long ROFF = 1048576l, RS = 262144l;
  long r0 = (long)blockIdx.y*64, c0 = (long)blockIdx.x*64;
  ush hh[16] __attribute__((aligned(16)));
  if (z==0){
    const long base = (r0+r)*1024 + c0 + cs;
    #pragma unroll
    for (int u=0;u<16;u++){
      float v = 2.f*(b2f(Xh[base+u]) + b2f(Xl[base+u])) - ((r0+r == c0+cs+u)?1.f:0.f);
      hh[u] = f2b(v);
      tb[r*65 + cs + u] = hh[u];
    }
    st16(&Qb[(r0+r)*1024 + c0 + cs], hh);
    __syncthreads();
    const int tr = threadIdx.x>>2, seg = threadIdx.x&3;
    #pragma unroll
    for (int u=0;u<16;u++) hh[u] = (ush)tb[(seg*16+u)*65 + tr];
    st16(&QTb[(c0+tr)*4096 + r0 + seg*16], hh);
  } else {
    if (blockIdx.x>=8 || blockIdx.y>=8) return;
    const int b = z-1;
    const long base = ROFF + (long)b*RS + (r0+r)*512 + c0 + cs;
    #pragma unroll
    for (int u=0;u<16;u++){
      float v = 2.f*(b2f(Xh[base+u]) + b2f(Xl[base+u])) - ((r0+r == c0+cs+u)?1.f:0.f);
      hh[u] = f2b(v);
      tb[r*65 + cs + u] = hh[u];
    }
    st16(&RKT[(long)b*524288 + (r0+r)*512 + c0 + cs], hh);
    __syncthreads();
    const int tr = threadIdx.x>>2, seg = threadIdx.x&3;
    #pragma unroll
    for (int u=0;u<16;u++) hh[u] = (ush)tb[(seg*16+u)*65 + tr];
    st16(&RK[(long)b*524288 + (c0+tr)*1024 + r0 + seg*16], hh);
  }
}

__global__ __launch_bounds__(256) void k_f2bf(const float* __restrict__ in, ush* __restrict__ o){
  long i = ((long)blockIdx.x*256 + threadIdx.x)*8;
  float4 a = *(const float4*)(in+i);
  float4 b = *(const float4*)(in+i+4);
  ush u[8] __attribute__((aligned(16)));
  u[0]=f2b(a.x);u[1]=f2b(a.y);u[2]=f2b(a.z);u[3]=f2b(a.w);
  u[4]=f2b(b.x);u[5]=f2b(b.y);u[6]=f2b(b.z);u[7]=f2b(b.w);
  *(int4*)(o+i) = *(const int4*)u;
}

// ------------------------------ host driver -------------------------------

static GA mk(const ush* Ah, const ush* Al, long lda,
             const ush* Bh, const ush* Bl, long ldb,
             int K, int M, int N, float alpha){
  GA g{}; g.ksplit=1<<30; g.A0h=Ah; g.A0l=Al; g.lda0=lda;
  g.Bh=Bh; g.Bl=Bl; g.ldb=ldb; g.K=K; g.M=M; g.N=N; g.alpha=alpha; g.beta=0.f;
  return g;
}

extern "C" void kernel_launch(void* const* d_in, const int* in_sizes, int n_in,
                              void* d_out, int out_size, void* d_ws, size_t ws_size,
                              hipStream_t stream)
{
  (void)in_sizes; (void)n_in; (void)out_size; (void)ws_size;
  const float* x   = (const float*)d_in[0];
  const float* Fq  = (const float*)d_in[1];
  const float* fqp = (const float*)d_in[2];
  const float* by  = (const float*)d_in[3];
  const float* Fr0 = (const float*)d_in[4];
  const float* Frr = (const float*)d_in[5];
  const float* frp = (const float*)d_in[6];
  const float* bp  = (const float*)d_in[7];
  float* out = (float*)d_out;

  const float SQG = sqrtf(10.0f - 0.1f);
  const float SQ2 = sqrtf(2.0f);
  const long UN = 3145728l;
  const long ROFF = 1048576l, RS = 262144l;

  char* base = (char*)d_ws;
  size_t off = 0;
  auto alloc = [&](size_t bytes)->char*{
    char* p = base + off; off = (off + bytes + 255) & ~(size_t)255; return p;
  };

  // ---- persistent ----
  ush* Qb  = (ush*)alloc(4194304l*2);
  ush* QTb = (ush*)alloc(4194304l*2);
  ush* RK  = (ush*)alloc(4194304l*2);
  ush* RKT = (ush*)alloc(4194304l*2);
  ush* xbf = (ush*)alloc(8388608l*2);
  float* scal = (float*)alloc(256*4);
  float* s2   = scal;
  float* bmax = scal + 16;
  float* cvl  = scal + 32;
  float* sc   = scal + 48;

  const size_t scratch0 = off;
  ush* Vh   = (ush*)alloc(UN*2);
  ush* Vl   = (ush*)alloc(UN*2);
  ush* Vth  = (ush*)alloc(UN*2);
  ush* Vtl  = (ush*)alloc(UN*2);
  ush* Wrh  = (ush*)alloc(1835008l*2);
  ush* Wrl  = (ush*)alloc(1835008l*2);
  ush* WrTh = (ush*)alloc(1835008l*2);
  ush* WrTl = (ush*)alloc(1835008l*2);
  float* PPf = (float*)alloc(UN*4);
  ush* Mh  = (ush*)alloc(UN*2);
  ush* Ml  = (ush*)alloc(UN*2);
  ush* MTh = (ush*)alloc(UN*2);
  ush* MTl = (ush*)alloc(UN*2);
  ush* Sh  = (ush*)alloc(UN*2);
  ush* XhA = (ush*)alloc(UN*2);
  ush* XhB = (ush*)alloc(UN*2);
  ush* XlA = (ush*)alloc(UN*2);
  ush* XlB = (ush*)alloc(UN*2);
  ush* XThA = (ush*)alloc(UN*2);
  ush* XThB = (ush*)alloc(UN*2);
  ush* XTlA = (ush*)alloc(UN*2);
  ush* XTlB = (ush*)alloc(UN*2);
  float* XfA = (float*)alloc(UN*4);
  float* XfB = (float*)alloc(UN*4);
  ush* Yh  = (ush*)alloc(UN*2);
  ush* Yl  = (ush*)alloc(UN*2);

  ush* Xh[2]  = {XhA, XhB};
  ush* Xl[2]  = {XlA, XlB};
  ush* XTh[2] = {XThA, XThB};
  ush* XTl[2] = {XTlA, XTlB};
  float* Xf[2] = {XfA, XfB};

  dim3 B256(256);
  GA ga{}, gr{};

  // ---- phase 0: norms & scales ----
  (void)hipMemsetAsync(scal, 0, 1024, stream);
  k_norms<<<dim3(64,9),B256,0,stream>>>(Fq, Fr0, Frr, s2);
  k_scales<<<1,16,0,stream>>>(s2, fqp, frp, sc);

  // ---- phase 1: build V / Wr (tiled, coalesced) ----
  k_buildT<<<dim3(16,48,8),B256,0,stream>>>(Fq, Frr, sc, Vh,Vl,Vth,Vtl, Wrh,Wrl,WrTh,WrTl);

  // PQ = V^T V ; PR_k = Wr Wr^T (split) -> PPf
  ga = mk(Vth,Vtl,3072, Vth,Vtl,3072, 3072,1024,1024, 1.f); ga.o0=PPf; ga.ldo0=1024;
  gr = mk(Wrh,Wrl,512, Wrh,Wrl,512, 512,512,512, 1.f);
  gr.sA=RS; gr.sB=RS; gr.o0=PPf+ROFF; gr.sO=RS; gr.ldo0=512;
  gemm_k<64,64,E_F32,true,false><<<dim3(16,16,8),B256,0,stream>>>(ga,gr,1);

  // ---- phase 2: assemble M, M^T (tiled) ----
  k_asmT<<<dim3(16,16,9),B256,0,stream>>>(Fq, Fr0, Frr, sc, PPf, Mh,Ml,MTh,MTl);

  // ---- phase 3: bound: S = M*M^T (bf16), S^2 (f32), rowabs, c, X0 ----
  ga = mk(Mh,nullptr,1024, Mh,nullptr,1024, 1024,1024,1024, 1.f); ga.o0=Sh; ga.ldo0=1024;
  gr = mk(Mh+ROFF,nullptr,512, Mh+ROFF,nullptr,512, 512,512,512, 1.f);
  gr.sA=RS; gr.sB=RS; gr.o0=Sh+ROFF; gr.sO=RS; gr.ldo0=512;
  gemm_k<64,64,E_BF16,false,false><<<dim3(16,16,9),B256,0,stream>>>(ga,gr,1);

  ga = mk(Sh,nullptr,1024, Sh,nullptr,1024, 1024,1024,1024, 1.f); ga.o0=PPf; ga.ldo0=1024;
  gr = mk(Sh+ROFF,nullptr,512, Sh+ROFF,nullptr,512, 512,512,512, 1.f);
  gr.sA=RS; gr.sB=RS; gr.o0=PPf+ROFF; gr.sO=RS; gr.ldo0=512;
  gemm_k<64,64,E_F32,false,false><<<dim3(16,16,9),B256,0,stream>>>(ga,gr,1);
  k_rowabs<<<dim3(1024,9),B256,0,stream>>>(PPf, bmax);
  k_makec<<<1,16,0,stream>>>(bmax, cvl);
  k_initX<<<12288,B256,0,stream>>>(Mh, MTh, cvl, Xh[0], XTh[0]);

  // ---- phase 4: coupled NS bf16: Y=(MX)^T ; X' = 2X - X*Y^T  (9 iters) ----
  int cur = 0;
  for (int it=0; it<9; ++it){
    int nxt = cur^1;
    ga = mk(XTh[cur],nullptr,1024, Mh,nullptr,1024, 1024,1024,1024, 1.f); ga.o0=Yh; ga.ldo0=1024;
    gr = mk(XTh[cur]+ROFF,nullptr,512, Mh+ROFF,nullptr,512, 512,512,512, 1.f);
    gr.sA=RS; gr.sB=RS; gr.o0=Yh+ROFF; gr.sO=RS; gr.ldo0=512;
    gemm_k<64,64,E_BF16,false,false><<<dim3(16,16,9),B256,0,stream>>>(ga,gr,1);

    ga = mk(Xh[cur],nullptr,1024, Yh,nullptr,1024, 1024,1024,1024, -1.f);
    ga.beta=2.f; ga.e0=Xh[cur];
    ga.o0=Xh[nxt]; ga.o1=XTh[nxt]; ga.ldo0=1024; ga.ldo1=1024;
    gr = mk(Xh[cur]+ROFF,nullptr,512, Yh+ROFF,nullptr,512, 512,512,512, -1.f);
    gr.beta=2.f; gr.e0=Xh[cur]+ROFF; gr.sD=RS;
    gr.sA=RS; gr.sB=RS; gr.sO=RS;
    gr.o0=Xh[nxt]+ROFF; gr.o1=XTh[nxt]+ROFF; gr.ldo0=512; gr.ldo1=512;
    gemm_k<64,64,E_BF16T2,false,true><<<dim3(16,16,9),B256,0,stream>>>(ga,gr,1);
    cur = nxt;
  }

  // ---- phase 5: promote + 2 split-precision NS iters ----
  k_promote<<<12288,B256,0,stream>>>(Xh[cur], Xf[cur], Xl[cur], XTl[cur]);
  for (int it=0; it<2; ++it){
    int nxt = cur^1;
    ga = mk(XTh[cur],XTl[cur],1024, Mh,Ml,1024, 1024,1024,1024, 1.f);
    ga.o1=Yh; ga.o2=Yl; ga.ldo0=1024;
    gr = mk(XTh[cur]+ROFF,XTl[cur]+ROFF,512, Mh+ROFF,Ml+ROFF,512, 512,512,512, 1.f);
    gr.sA=RS; gr.sB=RS; gr.o1=Yh+ROFF; gr.o2=Yl+ROFF; gr.sO=RS; gr.ldo0=512;
    gemm_k<64,64,E_SPLIT,true,false><<<dim3(16,16,9),B256,0,stream>>>(ga,gr,1);

    ga = mk(Xh[cur],Xl[cur],1024, Yh,Yl,1024, 1024,1024,1024, -1.f);
    ga.beta=2.f; ga.e0=Xf[cur];
    ga.o0=Xf[nxt]; ga.o1=Xh[nxt]; ga.o2=Xl[nxt]; ga.o3=XTh[nxt]; ga.o4=XTl[nxt];
    ga.ldo0=1024; ga.ldo1=1024;
    gr = mk(Xh[cur]+ROFF,Xl[cur]+ROFF,512, Yh+ROFF,Yl+ROFF,512, 512,512,512, -1.f);
    gr.beta=2.f; gr.e0=Xf[cur]+ROFF; gr.sD=RS;
    gr.sA=RS; gr.sB=RS; gr.sO=RS;
    gr.o0=Xf[nxt]+ROFF; gr.o1=Xh[nxt]+ROFF; gr.o2=Xl[nxt]+ROFF;
    gr.o3=XTh[nxt]+ROFF; gr.o4=XTl[nxt]+ROFF;
    gr.ldo0=512; gr.ldo1=512;
    gemm_k<64,64,E_SPLIT,true,true><<<dim3(16,16,9),B256,0,stream>>>(ga,gr,1);
    cur = nxt;
  }

  // ---- phase 6: tops = 2X - I (tiled) ; bottoms = -2*V*X (QW + LDS transpose) ----
  k_topT<<<dim3(16,16,9),B256,0,stream>>>(Xh[cur], Xl[cur], Qb, QTb, RK, RKT);

  ga = mk(Vh,Vl,1024, XTh[cur],XTl[cur],1024, 1024,3072,1024, -2.f);
  ga.o0=Qb + 1048576l; ga.ldo0=1024; ga.o1=QTb + 1024; ga.ldo1=4096;
  gr = mk(WrTh,WrTl,512, XTh[cur]+ROFF+RS, XTl[cur]+ROFF+RS, 512, 512,512,512, -2.f);
  gr.sA=RS; gr.sB=RS; gr.sO=524288;
  gr.o0=RKT + 524288 + 262144; gr.ldo0=512;
  gr.o1=RK + 524288 + 512; gr.ldo1=1024;
  gemm_k<64,64,E_QW,true,true><<<dim3(16,48,8),B256,0,stream>>>(ga,gr,1);

  // ---- main-path overlay buffers ----
  off = scratch0;
  ush* xh  = (ush*)alloc(33554432l*2);
  ush* yh  = (ush*)alloc(33554432l*2);
  ush* pre = (ush*)alloc(4194304l*2);
  ush* h0  = (ush*)alloc(4194304l*2);
  ush* h1  = (ush*)alloc(4194304l*2);

  // ---- phase 7: main chain ----
  k_f2bf<<<4096,B256,0,stream>>>(x, xbf);
  ga = mk(xbf,nullptr,1024, Qb,nullptr,1024, 1024,8192,4096, SQG);
  ga.o0=xh; ga.ldo0=4096;
  gemm_k<128,128,E_BF16,false,false><<<dim3(32,64,1),B256,0,stream>>>(ga,ga,1);

  for (int k=0;k<8;++k){
    ush* hprev = (k==0)? nullptr : (((k-1)&1) ? h1 : h0);
    ush* hnew  = (k&1) ? h1 : h0;
    GA gp_ = mk(xh + (long)k*512, nullptr, 4096,
                (k==0)? RKT : RK + (long)k*524288, nullptr, (k==0)?512:1024,
                (k==0)?512:1024, 8192, 512, SQ2);
    gp_.ksplit = 512; gp_.A1h = hprev; gp_.lda1 = 512;
    gp_.e0 = bp + (long)k*512; gp_.o0 = pre; gp_.ldo0 = 512;
    gemm_k<128,64,E_PRE,false,false><<<dim3(8,64,1),B256,0,stream>>>(gp_,gp_,1);

    GA gg = mk(pre, nullptr, 512,
               (k==0)? RK : RKT + (long)k*524288, nullptr, (k==0)?1024:512,
               512, 8192, (k==0)?512:1024, SQ2);
    gg.e0 = xh + (long)k*512; gg.ldE = 4096;
    gg.e1 = hprev;
    gg.o0 = hnew;
    gg.o1 = (k>=1)? (void*)(yh + (long)(k-1)*512) : nullptr;
    gg.o2 = (k==7)? (void*)(yh + 3584) : nullptr;
    if (k==0) gemm_k<128,64,E_GH,false,false><<<dim3(8,64,1),B256,0,stream>>>(gg,gg,1);
    else      gemm_k<128,128,E_GH,false,false><<<dim3(8,64,1),B256,0,stream>>>(gg,gg,1);
  }

  // out = 0.5*(10.1*x + sqrt_gam*(yh@Q)) + by
  ga = mk(yh,nullptr,4096, QTb,nullptr,4096, 4096,8192,1024, SQG);
  ga.e0=x; ga.e1=by; ga.o0=out; ga.ldo0=1024;
  gemm_k<128,128,E_OUT,false,false><<<dim3(8,64,1),B256,0,stream>>>(ga,ga,1);
}